// Round 3
// baseline (750.986 us; speedup 1.0000x reference)
//
#include <hip/hip_runtime.h>
#include <hip/hip_bf16.h>
#include <cstdint>

constexpr int HIDDEN = 128, CTXD = 2048, HEADS = 4, NLAYERS = 3, INDIM = 2176;

typedef __bf16 bf16x8 __attribute__((ext_vector_type(8)));
typedef float f32x4 __attribute__((ext_vector_type(4)));

static __device__ __forceinline__ unsigned short f2bf(float f) {
    union { float f; unsigned u; } v; v.f = f;
    unsigned r = v.u + 0x7fffu + ((v.u >> 16) & 1u);
    return (unsigned short)(r >> 16);
}
static __device__ __forceinline__ float bf2f(unsigned short s) {
    union { unsigned u; float f; } v; v.u = ((unsigned)s) << 16; return v.f;
}

// ---------------- weight transpose (f32 [B,R,C] -> bf16 [B,C,R]) ----------------
__global__ __launch_bounds__(256) void k_tr(const float* __restrict__ src,
                                            unsigned short* __restrict__ dst,
                                            int R, int C) {
    __shared__ unsigned short t[32][34];
    int b = blockIdx.z;
    int c0 = blockIdx.x * 32, r0 = blockIdx.y * 32;
    const float* s = src + (size_t)b * R * C;
    unsigned short* d = dst + (size_t)b * R * C;
    for (int rr = threadIdx.y; rr < 32; rr += 8) {
        int r = r0 + rr, c = c0 + threadIdx.x;
        unsigned short val = 0;
        if (r < R && c < C) val = f2bf(s[(size_t)r * C + c]);
        t[rr][threadIdx.x] = val;
    }
    __syncthreads();
    for (int rr = threadIdx.y; rr < 32; rr += 8) {
        int c = c0 + rr, r = r0 + threadIdx.x;
        if (c < C && r < R) d[(size_t)c * R + r] = t[threadIdx.x][rr];
    }
}

// ---------------- embedding gather ----------------
__global__ __launch_bounds__(256) void k_embed(const int* __restrict__ at,
                                               const float* __restrict__ W,
                                               const float* __restrict__ b,
                                               float* __restrict__ x,
                                               unsigned short* __restrict__ xc, int N) {
    int i = blockIdx.x * 256 + threadIdx.x;
    if (i >= N * HIDDEN) return;
    int n = i >> 7, c = i & 127;
    float v = W[(size_t)at[n] * HIDDEN + c] + b[c];
    x[i] = v;
    xc[(size_t)n * INDIM + c] = f2bf(v);
}

// ---------------- fused RBF + Linear(720->128) + BN + ReLU ----------------
__global__ __launch_bounds__(256) void k_rbf(const float* __restrict__ pos,
                                             const float* __restrict__ W1,
                                             const float* __restrict__ b1,
                                             const float* __restrict__ g,
                                             const float* __restrict__ bb,
                                             const float* __restrict__ bm,
                                             const float* __restrict__ bv,
                                             unsigned short* __restrict__ h, int N) {
    __shared__ float rbf[8 * 720];
    __shared__ float ps[24];
    int tid = threadIdx.x;
    int nb = blockIdx.x * 8;
    if (tid < 24) {
        int n = tid / 3, d = tid % 3;
        ps[tid] = (nb + n < N) ? pos[(size_t)(nb + n) * 3 + d] : 0.f;
    }
    __syncthreads();
    for (int i = tid; i < 5760; i += 256) {
        int n = i / 720, rem = i % 720, d = rem / 240, bin = rem % 240;
        float mu = -30.f + (60.f / 239.f) * (float)bin;
        float df = ps[n * 3 + d] - mu;
        rbf[i] = __expf(-0.5f * df * df);
    }
    __syncthreads();
    int c = tid & 127, ngp = tid >> 7;
    float a0 = 0.f, a1 = 0.f, a2 = 0.f, a3 = 0.f;
    const float* r0 = &rbf[(ngp * 4 + 0) * 720];
    const float* r1 = &rbf[(ngp * 4 + 1) * 720];
    const float* r2 = &rbf[(ngp * 4 + 2) * 720];
    const float* r3 = &rbf[(ngp * 4 + 3) * 720];
    for (int k = 0; k < 720; k++) {
        float w = W1[(size_t)k * 128 + c];
        a0 += r0[k] * w; a1 += r1[k] * w; a2 += r2[k] * w; a3 += r3[k] * w;
    }
    float sc = g[c] * rsqrtf(bv[c] + 1e-5f);
    float sh = bb[c] - bm[c] * sc;
    float accs[4] = {a0, a1, a2, a3};
#pragma unroll
    for (int i = 0; i < 4; i++) {
        int n = nb + ngp * 4 + i;
        if (n < N) {
            float y = (accs[i] + b1[c]) * sc + sh;
            y = fmaxf(y, 0.f);
            h[(size_t)n * 128 + c] = f2bf(y);
        }
    }
}

// ---------------- bf16 MFMA GEMM: C[M,N] = A[M,K] @ Bt[N,K]^T ----------------
// MODE 0: write bf16 C (ldc).  MODE 1: +bias[col]+ctx[batch[row]][col], write to C+128 col offset.
template <int MODE>
__global__ __launch_bounds__(256) void k_gemm(const unsigned short* __restrict__ A, int lda, int M,
                                              const unsigned short* __restrict__ Bt, int ldb,
                                              int K,
                                              unsigned short* __restrict__ C, int ldc,
                                              const int* __restrict__ batch,
                                              const float* __restrict__ ctx,
                                              const float* __restrict__ bias) {
    constexpr int LDT = 40;  // 32 + 4 pad (shorts); 80B rows -> 16B aligned, 2-way bank alias (free)
    __shared__ unsigned short As[128 * LDT];
    __shared__ unsigned short Bs[128 * LDT];
    const int tid = threadIdx.x;
    const int lane = tid & 63, wid = tid >> 6;
    const int m0 = blockIdx.x * 128, n0 = blockIdx.y * 128;
    const int wr = (wid >> 1) * 64, wc = (wid & 1) * 64;
    const int sr = tid >> 1, sk = (tid & 1) * 16;
    f32x4 acc[4][4];
#pragma unroll
    for (int i = 0; i < 4; i++)
#pragma unroll
        for (int j = 0; j < 4; j++)
#pragma unroll
            for (int r = 0; r < 4; r++) acc[i][j][r] = 0.f;
    const int nst = K / 32;
    const int arow = min(m0 + sr, M - 1);
    const unsigned short* ap = A + (size_t)arow * lda + sk;
    const unsigned short* bp = Bt + (size_t)(n0 + sr) * ldb + sk;
    uint4 av0 = *(const uint4*)ap, av1 = *(const uint4*)(ap + 8);
    uint4 bv0 = *(const uint4*)bp, bv1 = *(const uint4*)(bp + 8);
    const int fr = lane & 15, kg = lane >> 4;
    for (int ks = 0; ks < nst; ++ks) {
        __syncthreads();
        *(uint4*)&As[sr * LDT + sk] = av0;
        *(uint4*)&As[sr * LDT + sk + 8] = av1;
        *(uint4*)&Bs[sr * LDT + sk] = bv0;
        *(uint4*)&Bs[sr * LDT + sk + 8] = bv1;
        __syncthreads();
        if (ks + 1 < nst) {  // prefetch next K-step into regs, overlaps with MFMA below
            const unsigned short* ap2 = A + (size_t)arow * lda + (ks + 1) * 32 + sk;
            const unsigned short* bp2 = Bt + (size_t)(n0 + sr) * ldb + (ks + 1) * 32 + sk;
            av0 = *(const uint4*)ap2; av1 = *(const uint4*)(ap2 + 8);
            bv0 = *(const uint4*)bp2; bv1 = *(const uint4*)(bp2 + 8);
        }
        bf16x8 afr[4], bfr[4];
#pragma unroll
        for (int i = 0; i < 4; i++) {
            afr[i] = *reinterpret_cast<const bf16x8*>(&As[(wr + i * 16 + fr) * LDT + kg * 8]);
            bfr[i] = *reinterpret_cast<const bf16x8*>(&Bs[(wc + i * 16 + fr) * LDT + kg * 8]);
        }
#pragma unroll
        for (int i = 0; i < 4; i++)
#pragma unroll
            for (int j = 0; j < 4; j++)
                acc[i][j] = __builtin_amdgcn_mfma_f32_16x16x32_bf16(afr[i], bfr[j], acc[i][j], 0, 0, 0);
    }
    const int rg = lane >> 4;  // C/D: col = lane&15, row = (lane>>4)*4 + reg
#pragma unroll
    for (int i = 0; i < 4; i++) {
#pragma unroll
        for (int j = 0; j < 4; j++) {
            int col = n0 + wc + j * 16 + fr;
#pragma unroll
            for (int r = 0; r < 4; r++) {
                int row = m0 + wr + i * 16 + rg * 4 + r;
                if (row < M) {
                    float vv = acc[i][j][r];
                    if (MODE == 1) {
                        vv += bias[col] + ctx[(size_t)batch[row] * CTXD + col];
                        C[(size_t)row * ldc + HIDDEN + col] = f2bf(vv);
                    } else {
                        C[(size_t)row * ldc + col] = f2bf(vv);
                    }
                }
            }
        }
    }
}

// ---------------- attention logits: a_src/a_dst [N,4] ----------------
__global__ __launch_bounds__(256) void k_att(const unsigned short* __restrict__ xs,
                                             const float* __restrict__ att_s,
                                             const float* __restrict__ att_d,
                                             float* __restrict__ a_src,
                                             float* __restrict__ a_dst, int N) {
    int tid = threadIdx.x, lane = tid & 63, wid = tid >> 6;
    int n = blockIdx.x * 4 + wid;
    if (n >= N) return;
    int h = lane >> 4, c0 = (lane & 15) * 8;
    uint4 raw = *(const uint4*)(xs + (size_t)n * 512 + h * 128 + c0);
    const unsigned short* rs = (const unsigned short*)&raw;
    float ss = 0.f, sd = 0.f;
#pragma unroll
    for (int j = 0; j < 8; j++) {
        float xv = bf2f(rs[j]);
        ss += xv * att_s[h * 128 + c0 + j];
        sd += xv * att_d[h * 128 + c0 + j];
    }
#pragma unroll
    for (int d = 1; d < 16; d <<= 1) {
        ss += __shfl_xor(ss, d);
        sd += __shfl_xor(sd, d);
    }
    if ((lane & 15) == 0) {
        a_src[n * 4 + h] = ss;
        a_dst[n * 4 + h] = sd;
    }
}

// ---------------- CSR build ----------------
__global__ void k_cnt_init(int* cnt, int N) {
    int i = blockIdx.x * 256 + threadIdx.x;
    if (i < N) cnt[i] = 1;  // self-loop
}
__global__ void k_cnt(const int* __restrict__ ei, int E, int* cnt) {
    int i = blockIdx.x * 256 + threadIdx.x;
    if (i < E) atomicAdd(&cnt[ei[E + i]], 1);
}
__global__ __launch_bounds__(1024) void k_scan(const int* __restrict__ cnt, int* __restrict__ rowptr,
                                               int* __restrict__ cursor, int n) {
    __shared__ int wsum[16];
    __shared__ int carry;
    int tid = threadIdx.x, lane = tid & 63, wid = tid >> 6;
    if (tid == 0) carry = 0;
    __syncthreads();
    for (int basei = 0; basei < n; basei += 1024) {
        int i = basei + tid;
        int v = (i < n) ? cnt[i] : 0;
        int s = v;
#pragma unroll
        for (int d = 1; d < 64; d <<= 1) {
            int t = __shfl_up(s, (unsigned)d);
            if (lane >= d) s += t;
        }
        if (lane == 63) wsum[wid] = s;
        __syncthreads();
        if (wid == 0 && lane < 16) {
            int ws = wsum[lane]; int t = ws;
#pragma unroll
            for (int d = 1; d < 16; d <<= 1) {
                int u = __shfl_up(t, (unsigned)d);
                if (lane >= d) t += u;
            }
            wsum[lane] = t - ws;  // exclusive wave offsets
        }
        __syncthreads();
        int excl = carry + wsum[wid] + (s - v);
        if (i < n) { rowptr[i] = excl; cursor[i] = excl; }
        __syncthreads();
        if (tid == 1023) carry += wsum[15] + s;
        __syncthreads();
    }
    if (tid == 0) rowptr[n] = carry;
}
__global__ void k_fill(const int* __restrict__ ei, int E, int N, int* cursor, int* csrc) {
    int i = blockIdx.x * 256 + threadIdx.x;
    if (i >= E + N) return;
    int s, d;
    if (i < E) { s = ei[i]; d = ei[E + i]; }
    else { s = i - E; d = s; }
    int slot = atomicAdd(&cursor[d], 1);
    csrc[slot] = s;
}

// ---------------- GAT aggregation + softmax + BN + GELU + residual ----------------
__global__ __launch_bounds__(256) void k_agg(const int* __restrict__ rowptr,
                                             const int* __restrict__ csrc,
                                             const float* __restrict__ asrc,
                                             const float* __restrict__ adstv,
                                             const unsigned short* __restrict__ xs,
                                             const float* __restrict__ gbias,
                                             const float* __restrict__ bg,
                                             const float* __restrict__ bb,
                                             const float* __restrict__ bm,
                                             const float* __restrict__ bv,
                                             float* __restrict__ x,
                                             unsigned short* __restrict__ xc, int N) {
    int tid = threadIdx.x, lane = tid & 63, wid = tid >> 6;
    int n = blockIdx.x * 4 + wid;
    if (n >= N) return;
    int beg = rowptr[n], end = rowptr[n + 1];
    float ad[4];
#pragma unroll
    for (int hh = 0; hh < 4; hh++) ad[hh] = adstv[n * 4 + hh];
    // pass 1: per-head max
    float mx[4] = {-1e30f, -1e30f, -1e30f, -1e30f};
    for (int e = beg + lane; e < end; e += 64) {
        int s = csrc[e];
#pragma unroll
        for (int hh = 0; hh < 4; hh++) {
            float a = asrc[s * 4 + hh] + ad[hh];
            a = a > 0.f ? a : 0.2f * a;
            mx[hh] = fmaxf(mx[hh], a);
        }
    }
#pragma unroll
    for (int d = 1; d < 64; d <<= 1)
#pragma unroll
        for (int hh = 0; hh < 4; hh++) mx[hh] = fmaxf(mx[hh], __shfl_xor(mx[hh], d));
    // pass 2: denom
    float sm[4] = {0.f, 0.f, 0.f, 0.f};
    for (int e = beg + lane; e < end; e += 64) {
        int s = csrc[e];
#pragma unroll
        for (int hh = 0; hh < 4; hh++) {
            float a = asrc[s * 4 + hh] + ad[hh];
            a = a > 0.f ? a : 0.2f * a;
            sm[hh] += __expf(a - mx[hh]);
        }
    }
#pragma unroll
    for (int d = 1; d < 64; d <<= 1)
#pragma unroll
        for (int hh = 0; hh < 4; hh++) sm[hh] += __shfl_xor(sm[hh], d);
    // pass 3: weighted message accumulation. lane covers head h, channels c0..c0+7
    int h = lane >> 4, c0 = (lane & 15) * 8;
    float am = mx[h], iv = 1.f / fmaxf(sm[h], 1e-16f), adh = ad[h];
    float acc[8];
#pragma unroll
    for (int j = 0; j < 8; j++) acc[j] = 0.f;
    for (int e = beg; e < end; e++) {
        int s = csrc[e];
        float a = asrc[s * 4 + h] + adh;
        a = a > 0.f ? a : 0.2f * a;
        float w = __expf(a - am) * iv;
        uint4 raw = *(const uint4*)(xs + (size_t)s * 512 + h * 128 + c0);
        const unsigned short* rs = (const unsigned short*)&raw;
#pragma unroll
        for (int j = 0; j < 8; j++) acc[j] += w * bf2f(rs[j]);
    }
    // head mean across lanes (h = lane>>4)
#pragma unroll
    for (int j = 0; j < 8; j++) {
        acc[j] += __shfl_xor(acc[j], 16);
        acc[j] += __shfl_xor(acc[j], 32);
    }
    if (lane < 16) {
#pragma unroll
        for (int j = 0; j < 8; j++) {
            int c = c0 + j;
            float t = acc[j] * 0.25f + gbias[c];
            float sc = bg[c] * rsqrtf(bv[c] + 1e-5f);
            float y = (t - bm[c]) * sc + bb[c];
            float ge = 0.5f * y * (1.f + erff(y * 0.70710678118f));
            float xn = x[(size_t)n * 128 + c] + ge;
            x[(size_t)n * 128 + c] = xn;
            xc[(size_t)n * INDIM + c] = f2bf(xn);
        }
    }
}

// ---------------- fused pool + final linear ----------------
__global__ __launch_bounds__(256) void k_pool(const float* __restrict__ x,
                                              const int* __restrict__ batch,
                                              const float* __restrict__ W,
                                              const float* __restrict__ bo,
                                              float* __restrict__ out, int N) {
    __shared__ float xg[128];
    __shared__ float tmp[256];
    __shared__ int bounds[2];
    int g = blockIdx.x, tid = threadIdx.x;
    if (tid < 2) {
        int key = g + tid, lo = 0, hi = N;
        while (lo < hi) { int mid = (lo + hi) >> 1; if (batch[mid] < key) lo = mid + 1; else hi = mid; }
        bounds[tid] = lo;
    }
    __syncthreads();
    int s = bounds[0], e = bounds[1];
    int c = tid & 127, rgp = tid >> 7;
    float a = 0.f;
    for (int n = s + rgp; n < e; n += 2) a += x[(size_t)n * 128 + c];
    tmp[tid] = a;
    __syncthreads();
    if (tid < 128) xg[tid] = tmp[tid] + tmp[tid + 128];
    __syncthreads();
    float cntf = (float)(e - s);
    for (int j = tid; j < 1024; j += 256) {
        float o = cntf * bo[j];
        for (int cc = 0; cc < 128; cc++) o += xg[cc] * W[(size_t)cc * 1024 + j];
        out[(size_t)g * 1024 + j] = o;
    }
}

extern "C" void kernel_launch(void* const* d_in, const int* in_sizes, int n_in,
                              void* d_out, int out_size, void* d_ws, size_t ws_size,
                              hipStream_t stream) {
    const int N = in_sizes[0];
    const int E = in_sizes[2] / 2;
    const int NG = in_sizes[5] / CTXD;
    const int* at = (const int*)d_in[0];
    const float* pos = (const float*)d_in[1];
    const int* ei = (const int*)d_in[2];
    const int* batch = (const int*)d_in[4];
    const float* ctx = (const float*)d_in[5];
    const float* embW = (const float*)d_in[6];
    const float* embB = (const float*)d_in[7];
    const float* W1 = (const float*)d_in[8];
    const float* b1 = (const float*)d_in[9];
    const float* rg = (const float*)d_in[10];
    const float* rb = (const float*)d_in[11];
    const float* rm = (const float*)d_in[12];
    const float* rv = (const float*)d_in[13];
    const float* W2 = (const float*)d_in[14];
    const float* b2 = (const float*)d_in[15];
    const float* gatW = (const float*)d_in[16];
    const float* atts = (const float*)d_in[17];
    const float* attd = (const float*)d_in[18];
    const float* gbias = (const float*)d_in[19];
    const float* bg = (const float*)d_in[20];
    const float* bbb = (const float*)d_in[21];
    const float* bm = (const float*)d_in[22];
    const float* bv = (const float*)d_in[23];
    const float* outW = (const float*)d_in[24];
    const float* outb = (const float*)d_in[25];
    float* out = (float*)d_out;

    char* basep = (char*)d_ws;
    size_t off = 0;
    auto alloc = [&](size_t bytes) -> char* {
        char* p = basep + off;
        off = (off + bytes + 255) & ~(size_t)255;
        return p;
    };
    unsigned short* xc = (unsigned short*)alloc((size_t)N * INDIM * 2);
    float* x = (float*)alloc((size_t)N * 128 * 4);
    unsigned short* h = (unsigned short*)alloc((size_t)N * 128 * 2);
    unsigned short* xs = (unsigned short*)alloc((size_t)N * 512 * 2);
    float* a_src = (float*)alloc((size_t)N * 4 * 4);
    float* a_dst = (float*)alloc((size_t)N * 4 * 4);
    int* cnt = (int*)alloc((size_t)N * 4);
    int* rowptr = (int*)alloc((size_t)(N + 1) * 4);
    int* cursor = (int*)alloc((size_t)N * 4);
    int* csrc = (int*)alloc((size_t)(E + N) * 4);
    unsigned short* gatWt = (unsigned short*)alloc((size_t)NLAYERS * 512 * INDIM * 2);
    unsigned short* W2t = (unsigned short*)alloc((size_t)CTXD * 128 * 2);
    (void)ws_size; (void)n_in; (void)out_size;

    // weight prep
    {
        dim3 b(32, 8);
        dim3 g1((512 + 31) / 32, (INDIM + 31) / 32, NLAYERS);
        k_tr<<<g1, b, 0, stream>>>(gatW, gatWt, INDIM, 512);
        dim3 g2((CTXD + 31) / 32, (128 + 31) / 32, 1);
        k_tr<<<g2, b, 0, stream>>>(W2, W2t, 128, CTXD);
    }
    k_embed<<<(N * 128 + 255) / 256, 256, 0, stream>>>(at, embW, embB, x, xc, N);
    k_rbf<<<(N + 7) / 8, 256, 0, stream>>>(pos, W1, b1, rg, rb, rm, rv, h, N);
    {
        dim3 g((N + 127) / 128, CTXD / 128);
        k_gemm<1><<<g, 256, 0, stream>>>(h, 128, N, W2t, 128, 128, xc, INDIM, batch, ctx, b2);
    }
    // CSR (dst-sorted incoming edges incl. self-loops)
    k_cnt_init<<<(N + 255) / 256, 256, 0, stream>>>(cnt, N);
    k_cnt<<<(E + 255) / 256, 256, 0, stream>>>(ei, E, cnt);
    k_scan<<<1, 1024, 0, stream>>>(cnt, rowptr, cursor, N);
    k_fill<<<(E + N + 255) / 256, 256, 0, stream>>>(ei, E, N, cursor, csrc);
    // GAT layers
    {
        dim3 g((N + 127) / 128, 512 / 128);
        for (int l = 0; l < NLAYERS; l++) {
            k_gemm<0><<<g, 256, 0, stream>>>(xc, INDIM, N, gatWt + (size_t)l * 512 * INDIM, INDIM,
                                             INDIM, xs, 512, nullptr, nullptr, nullptr);
            k_att<<<(N + 3) / 4, 256, 0, stream>>>(xs, atts + l * HEADS * 128, attd + l * HEADS * 128,
                                                   a_src, a_dst, N);
            k_agg<<<(N + 3) / 4, 256, 0, stream>>>(rowptr, csrc, a_src, a_dst, xs,
                                                   gbias + l * 128, bg + l * 128, bbb + l * 128,
                                                   bm + l * 128, bv + l * 128, x, xc, N);
        }
    }
    k_pool<<<NG, 256, 0, stream>>>(x, batch, outW, outb, out, N);
}

// Round 4
// 662.132 us; speedup vs baseline: 1.1342x; 1.1342x over previous
//
#include <hip/hip_runtime.h>
#include <hip/hip_bf16.h>
#include <cstdint>

constexpr int HIDDEN = 128, CTXD = 2048, HEADS = 4, NLAYERS = 3, INDIM = 2176;
constexpr int KRBF = 720, KPAD = 736;  // 736 = 23 * 32

typedef __bf16 bf16x8 __attribute__((ext_vector_type(8)));
typedef float f32x4 __attribute__((ext_vector_type(4)));

static __device__ __forceinline__ unsigned short f2bf(float f) {
    union { float f; unsigned u; } v; v.f = f;
    unsigned r = v.u + 0x7fffu + ((v.u >> 16) & 1u);
    return (unsigned short)(r >> 16);
}
static __device__ __forceinline__ float bf2f(unsigned short s) {
    union { unsigned u; float f; } v; v.u = ((unsigned)s) << 16; return v.f;
}

// ---------------- weight transpose (f32 [B,R,C] -> bf16 [B,C,R]) ----------------
__global__ __launch_bounds__(256) void k_tr(const float* __restrict__ src,
                                            unsigned short* __restrict__ dst,
                                            int R, int C) {
    __shared__ unsigned short t[32][34];
    int b = blockIdx.z;
    int c0 = blockIdx.x * 32, r0 = blockIdx.y * 32;
    const float* s = src + (size_t)b * R * C;
    unsigned short* d = dst + (size_t)b * R * C;
    for (int rr = threadIdx.y; rr < 32; rr += 8) {
        int r = r0 + rr, c = c0 + threadIdx.x;
        unsigned short val = 0;
        if (r < R && c < C) val = f2bf(s[(size_t)r * C + c]);
        t[rr][threadIdx.x] = val;
    }
    __syncthreads();
    for (int rr = threadIdx.y; rr < 32; rr += 8) {
        int c = c0 + rr, r = r0 + threadIdx.x;
        if (c < C && r < R) d[(size_t)c * R + r] = t[threadIdx.x][rr];
    }
}

// ---------------- W1 transpose to bf16 [128][KPAD], zero-padded K ----------------
__global__ __launch_bounds__(256) void k_trW1(const float* __restrict__ W1,
                                              unsigned short* __restrict__ W1t) {
    int i = blockIdx.x * 256 + threadIdx.x;
    if (i >= 128 * KPAD) return;
    int c = i / KPAD, k = i % KPAD;
    unsigned short v = 0;
    if (k < KRBF) v = f2bf(W1[(size_t)k * 128 + c]);
    W1t[i] = v;
}

// ---------------- embedding gather ----------------
__global__ __launch_bounds__(256) void k_embed(const int* __restrict__ at,
                                               const float* __restrict__ W,
                                               const float* __restrict__ b,
                                               float* __restrict__ x,
                                               unsigned short* __restrict__ xc, int N) {
    int i = blockIdx.x * 256 + threadIdx.x;
    if (i >= N * HIDDEN) return;
    int n = i >> 7, c = i & 127;
    float v = W[(size_t)at[n] * HIDDEN + c] + b[c];
    x[i] = v;
    xc[(size_t)n * INDIM + c] = f2bf(v);
}

// ---------------- fused RBF + Linear(720->128) via MFMA + BN + ReLU ----------------
// A[128 nodes][32 k] computed in-register (exp), B = W1t bf16 [128][KPAD].
__global__ __launch_bounds__(256) void k_rbf_mfma(const float* __restrict__ pos,
                                                  const unsigned short* __restrict__ W1t,
                                                  const float* __restrict__ b1,
                                                  const float* __restrict__ g,
                                                  const float* __restrict__ bb,
                                                  const float* __restrict__ bm,
                                                  const float* __restrict__ bv,
                                                  unsigned short* __restrict__ h, int N) {
    constexpr int LDT = 40;
    __shared__ unsigned short As[128 * LDT];
    __shared__ unsigned short Bs[128 * LDT];
    __shared__ float ps[128 * 3];
    const int tid = threadIdx.x;
    const int lane = tid & 63, wid = tid >> 6;
    const int nb = blockIdx.x * 128;
    for (int i = tid; i < 384; i += 256) {
        int n = nb + i / 3;
        ps[i] = (n < N) ? pos[(size_t)n * 3 + (i % 3)] : 1.0e9f;  // pad rows -> rbf = 0
    }
    __syncthreads();
    const int sr = tid >> 1, sk = (tid & 1) * 16;
    const int wr = (wid >> 1) * 64, wc = (wid & 1) * 64;
    const int fr = lane & 15, kg = lane >> 4;
    f32x4 acc[4][4];
#pragma unroll
    for (int i = 0; i < 4; i++)
#pragma unroll
        for (int j = 0; j < 4; j++)
#pragma unroll
            for (int r = 0; r < 4; r++) acc[i][j][r] = 0.f;
    const float p0 = ps[sr * 3], p1 = ps[sr * 3 + 1], p2 = ps[sr * 3 + 2];
    const unsigned short* bp = W1t + (size_t)sr * KPAD + sk;
    uint4 bv0 = *(const uint4*)bp, bv1 = *(const uint4*)(bp + 8);
    constexpr int NST = KPAD / 32;
    for (int ks = 0; ks < NST; ++ks) {
        unsigned short av[16];
#pragma unroll
        for (int j = 0; j < 16; j++) {
            int kglob = ks * 32 + sk + j;
            float v = 0.f;
            if (kglob < KRBF) {
                int d = kglob / 240, bin = kglob % 240;
                float mu = -30.f + (60.f / 239.f) * (float)bin;
                float p = (d == 0) ? p0 : ((d == 1) ? p1 : p2);
                float df = p - mu;
                v = __expf(-0.5f * df * df);
            }
            av[j] = f2bf(v);
        }
        __syncthreads();
        *(uint4*)&As[sr * LDT + sk] = *(const uint4*)&av[0];
        *(uint4*)&As[sr * LDT + sk + 8] = *(const uint4*)&av[8];
        *(uint4*)&Bs[sr * LDT + sk] = bv0;
        *(uint4*)&Bs[sr * LDT + sk + 8] = bv1;
        __syncthreads();
        if (ks + 1 < NST) {
            const unsigned short* bp2 = W1t + (size_t)sr * KPAD + (ks + 1) * 32 + sk;
            bv0 = *(const uint4*)bp2;
            bv1 = *(const uint4*)(bp2 + 8);
        }
        bf16x8 afr[4], bfr[4];
#pragma unroll
        for (int i = 0; i < 4; i++) {
            afr[i] = *reinterpret_cast<const bf16x8*>(&As[(wr + i * 16 + fr) * LDT + kg * 8]);
            bfr[i] = *reinterpret_cast<const bf16x8*>(&Bs[(wc + i * 16 + fr) * LDT + kg * 8]);
        }
#pragma unroll
        for (int i = 0; i < 4; i++)
#pragma unroll
            for (int j = 0; j < 4; j++)
                acc[i][j] = __builtin_amdgcn_mfma_f32_16x16x32_bf16(afr[i], bfr[j], acc[i][j], 0, 0, 0);
    }
    const int rg = lane >> 4;
#pragma unroll
    for (int i = 0; i < 4; i++) {
#pragma unroll
        for (int j = 0; j < 4; j++) {
            int col = wc + j * 16 + fr;
            float sc = g[col] * rsqrtf(bv[col] + 1e-5f);
            float sh = bb[col] - bm[col] * sc;
            float bc = b1[col];
#pragma unroll
            for (int r = 0; r < 4; r++) {
                int row = nb + wr + i * 16 + rg * 4 + r;
                if (row < N) {
                    float y = (acc[i][j][r] + bc) * sc + sh;
                    y = fmaxf(y, 0.f);
                    h[(size_t)row * 128 + col] = f2bf(y);
                }
            }
        }
    }
}

// ---------------- bf16 MFMA GEMM: C[M,N] = A[M,K] @ Bt[N,K]^T ----------------
// MODE 0: write bf16 C (ldc).  MODE 1: +bias[col]+ctx[batch[row]][col], write to C+128 col offset.
template <int MODE>
__global__ __launch_bounds__(256) void k_gemm(const unsigned short* __restrict__ A, int lda, int M,
                                              const unsigned short* __restrict__ Bt, int ldb,
                                              int K,
                                              unsigned short* __restrict__ C, int ldc,
                                              const int* __restrict__ batch,
                                              const float* __restrict__ ctx,
                                              const float* __restrict__ bias) {
    constexpr int LDT = 40;  // 32 + 4 pad (shorts); 80B rows -> 16B aligned, 2-way bank alias (free)
    __shared__ unsigned short As[128 * LDT];
    __shared__ unsigned short Bs[128 * LDT];
    const int tid = threadIdx.x;
    const int lane = tid & 63, wid = tid >> 6;
    const int m0 = blockIdx.x * 128, n0 = blockIdx.y * 128;
    const int wr = (wid >> 1) * 64, wc = (wid & 1) * 64;
    const int sr = tid >> 1, sk = (tid & 1) * 16;
    f32x4 acc[4][4];
#pragma unroll
    for (int i = 0; i < 4; i++)
#pragma unroll
        for (int j = 0; j < 4; j++)
#pragma unroll
            for (int r = 0; r < 4; r++) acc[i][j][r] = 0.f;
    const int nst = K / 32;
    const int arow = min(m0 + sr, M - 1);
    const unsigned short* ap = A + (size_t)arow * lda + sk;
    const unsigned short* bp = Bt + (size_t)(n0 + sr) * ldb + sk;
    uint4 av0 = *(const uint4*)ap, av1 = *(const uint4*)(ap + 8);
    uint4 bv0 = *(const uint4*)bp, bv1 = *(const uint4*)(bp + 8);
    const int fr = lane & 15, kg = lane >> 4;
    for (int ks = 0; ks < nst; ++ks) {
        __syncthreads();
        *(uint4*)&As[sr * LDT + sk] = av0;
        *(uint4*)&As[sr * LDT + sk + 8] = av1;
        *(uint4*)&Bs[sr * LDT + sk] = bv0;
        *(uint4*)&Bs[sr * LDT + sk + 8] = bv1;
        __syncthreads();
        if (ks + 1 < nst) {  // prefetch next K-step into regs, overlaps with MFMA below
            const unsigned short* ap2 = A + (size_t)arow * lda + (ks + 1) * 32 + sk;
            const unsigned short* bp2 = Bt + (size_t)(n0 + sr) * ldb + (ks + 1) * 32 + sk;
            av0 = *(const uint4*)ap2; av1 = *(const uint4*)(ap2 + 8);
            bv0 = *(const uint4*)bp2; bv1 = *(const uint4*)(bp2 + 8);
        }
        bf16x8 afr[4], bfr[4];
#pragma unroll
        for (int i = 0; i < 4; i++) {
            afr[i] = *reinterpret_cast<const bf16x8*>(&As[(wr + i * 16 + fr) * LDT + kg * 8]);
            bfr[i] = *reinterpret_cast<const bf16x8*>(&Bs[(wc + i * 16 + fr) * LDT + kg * 8]);
        }
#pragma unroll
        for (int i = 0; i < 4; i++)
#pragma unroll
            for (int j = 0; j < 4; j++)
                acc[i][j] = __builtin_amdgcn_mfma_f32_16x16x32_bf16(afr[i], bfr[j], acc[i][j], 0, 0, 0);
    }
    const int rg = lane >> 4;  // C/D: col = lane&15, row = (lane>>4)*4 + reg
#pragma unroll
    for (int i = 0; i < 4; i++) {
#pragma unroll
        for (int j = 0; j < 4; j++) {
            int col = n0 + wc + j * 16 + fr;
#pragma unroll
            for (int r = 0; r < 4; r++) {
                int row = m0 + wr + i * 16 + rg * 4 + r;
                if (row < M) {
                    float vv = acc[i][j][r];
                    if (MODE == 1) {
                        vv += bias[col] + ctx[(size_t)batch[row] * CTXD + col];
                        C[(size_t)row * ldc + HIDDEN + col] = f2bf(vv);
                    } else {
                        C[(size_t)row * ldc + col] = f2bf(vv);
                    }
                }
            }
        }
    }
}

// ---------------- attention logits: a_src/a_dst [N,4] ----------------
__global__ __launch_bounds__(256) void k_att(const unsigned short* __restrict__ xs,
                                             const float* __restrict__ att_s,
                                             const float* __restrict__ att_d,
                                             float* __restrict__ a_src,
                                             float* __restrict__ a_dst, int N) {
    int tid = threadIdx.x, lane = tid & 63, wid = tid >> 6;
    int n = blockIdx.x * 4 + wid;
    if (n >= N) return;
    int h = lane >> 4, c0 = (lane & 15) * 8;
    uint4 raw = *(const uint4*)(xs + (size_t)n * 512 + h * 128 + c0);
    const unsigned short* rs = (const unsigned short*)&raw;
    float ss = 0.f, sd = 0.f;
#pragma unroll
    for (int j = 0; j < 8; j++) {
        float xv = bf2f(rs[j]);
        ss += xv * att_s[h * 128 + c0 + j];
        sd += xv * att_d[h * 128 + c0 + j];
    }
#pragma unroll
    for (int d = 1; d < 16; d <<= 1) {
        ss += __shfl_xor(ss, d);
        sd += __shfl_xor(sd, d);
    }
    if ((lane & 15) == 0) {
        a_src[n * 4 + h] = ss;
        a_dst[n * 4 + h] = sd;
    }
}

// ---------------- CSR build ----------------
__global__ void k_cnt_init(int* cnt, int N) {
    int i = blockIdx.x * 256 + threadIdx.x;
    if (i < N) cnt[i] = 1;  // self-loop
}
__global__ void k_cnt(const int* __restrict__ ei, int E, int* cnt) {
    int i = blockIdx.x * 256 + threadIdx.x;
    if (i < E) atomicAdd(&cnt[ei[E + i]], 1);
}
__global__ __launch_bounds__(1024) void k_scan(const int* __restrict__ cnt, int* __restrict__ rowptr,
                                               int* __restrict__ cursor, int n) {
    __shared__ int wsum[16];
    __shared__ int carry;
    int tid = threadIdx.x, lane = tid & 63, wid = tid >> 6;
    if (tid == 0) carry = 0;
    __syncthreads();
    for (int basei = 0; basei < n; basei += 1024) {
        int i = basei + tid;
        int v = (i < n) ? cnt[i] : 0;
        int s = v;
#pragma unroll
        for (int d = 1; d < 64; d <<= 1) {
            int t = __shfl_up(s, (unsigned)d);
            if (lane >= d) s += t;
        }
        if (lane == 63) wsum[wid] = s;
        __syncthreads();
        if (wid == 0 && lane < 16) {
            int ws = wsum[lane]; int t = ws;
#pragma unroll
            for (int d = 1; d < 16; d <<= 1) {
                int u = __shfl_up(t, (unsigned)d);
                if (lane >= d) t += u;
            }
            wsum[lane] = t - ws;  // exclusive wave offsets
        }
        __syncthreads();
        int excl = carry + wsum[wid] + (s - v);
        if (i < n) { rowptr[i] = excl; cursor[i] = excl; }
        __syncthreads();
        if (tid == 1023) carry += wsum[15] + s;
        __syncthreads();
    }
    if (tid == 0) rowptr[n] = carry;
}
__global__ void k_fill(const int* __restrict__ ei, int E, int N, int* cursor, int* csrc) {
    int i = blockIdx.x * 256 + threadIdx.x;
    if (i >= E + N) return;
    int s, d;
    if (i < E) { s = ei[i]; d = ei[E + i]; }
    else { s = i - E; d = s; }
    int slot = atomicAdd(&cursor[d], 1);
    csrc[slot] = s;
}

// ---------------- GAT aggregation + softmax + BN + GELU + residual ----------------
__global__ __launch_bounds__(256) void k_agg(const int* __restrict__ rowptr,
                                             const int* __restrict__ csrc,
                                             const float* __restrict__ asrc,
                                             const float* __restrict__ adstv,
                                             const unsigned short* __restrict__ xs,
                                             const float* __restrict__ gbias,
                                             const float* __restrict__ bg,
                                             const float* __restrict__ bb,
                                             const float* __restrict__ bm,
                                             const float* __restrict__ bv,
                                             float* __restrict__ x,
                                             unsigned short* __restrict__ xc, int N) {
    int tid = threadIdx.x, lane = tid & 63, wid = tid >> 6;
    int n = blockIdx.x * 4 + wid;
    if (n >= N) return;
    int beg = rowptr[n], end = rowptr[n + 1];
    float ad[4];
#pragma unroll
    for (int hh = 0; hh < 4; hh++) ad[hh] = adstv[n * 4 + hh];
    // pass 1: per-head max
    float mx[4] = {-1e30f, -1e30f, -1e30f, -1e30f};
    for (int e = beg + lane; e < end; e += 64) {
        int s = csrc[e];
#pragma unroll
        for (int hh = 0; hh < 4; hh++) {
            float a = asrc[s * 4 + hh] + ad[hh];
            a = a > 0.f ? a : 0.2f * a;
            mx[hh] = fmaxf(mx[hh], a);
        }
    }
#pragma unroll
    for (int d = 1; d < 64; d <<= 1)
#pragma unroll
        for (int hh = 0; hh < 4; hh++) mx[hh] = fmaxf(mx[hh], __shfl_xor(mx[hh], d));
    // pass 2: denom
    float sm[4] = {0.f, 0.f, 0.f, 0.f};
    for (int e = beg + lane; e < end; e += 64) {
        int s = csrc[e];
#pragma unroll
        for (int hh = 0; hh < 4; hh++) {
            float a = asrc[s * 4 + hh] + ad[hh];
            a = a > 0.f ? a : 0.2f * a;
            sm[hh] += __expf(a - mx[hh]);
        }
    }
#pragma unroll
    for (int d = 1; d < 64; d <<= 1)
#pragma unroll
        for (int hh = 0; hh < 4; hh++) sm[hh] += __shfl_xor(sm[hh], d);
    // pass 3: weighted message accumulation. lane covers head h, channels c0..c0+7
    int h = lane >> 4, c0 = (lane & 15) * 8;
    float am = mx[h], iv = 1.f / fmaxf(sm[h], 1e-16f), adh = ad[h];
    float acc[8];
#pragma unroll
    for (int j = 0; j < 8; j++) acc[j] = 0.f;
    for (int e = beg; e < end; e++) {
        int s = csrc[e];
        float a = asrc[s * 4 + h] + adh;
        a = a > 0.f ? a : 0.2f * a;
        float w = __expf(a - am) * iv;
        uint4 raw = *(const uint4*)(xs + (size_t)s * 512 + h * 128 + c0);
        const unsigned short* rs = (const unsigned short*)&raw;
#pragma unroll
        for (int j = 0; j < 8; j++) acc[j] += w * bf2f(rs[j]);
    }
    // head mean across lanes (h = lane>>4)
#pragma unroll
    for (int j = 0; j < 8; j++) {
        acc[j] += __shfl_xor(acc[j], 16);
        acc[j] += __shfl_xor(acc[j], 32);
    }
    if (lane < 16) {
#pragma unroll
        for (int j = 0; j < 8; j++) {
            int c = c0 + j;
            float t = acc[j] * 0.25f + gbias[c];
            float sc = bg[c] * rsqrtf(bv[c] + 1e-5f);
            float y = (t - bm[c]) * sc + bb[c];
            float ge = 0.5f * y * (1.f + erff(y * 0.70710678118f));
            float xn = x[(size_t)n * 128 + c] + ge;
            x[(size_t)n * 128 + c] = xn;
            xc[(size_t)n * INDIM + c] = f2bf(xn);
        }
    }
}

// ---------------- fused pool + final linear ----------------
__global__ __launch_bounds__(256) void k_pool(const float* __restrict__ x,
                                              const int* __restrict__ batch,
                                              const float* __restrict__ W,
                                              const float* __restrict__ bo,
                                              float* __restrict__ out, int N) {
    __shared__ float xg[128];
    __shared__ float tmp[256];
    __shared__ int bounds[2];
    int g = blockIdx.x, tid = threadIdx.x;
    if (tid < 2) {
        int key = g + tid, lo = 0, hi = N;
        while (lo < hi) { int mid = (lo + hi) >> 1; if (batch[mid] < key) lo = mid + 1; else hi = mid; }
        bounds[tid] = lo;
    }
    __syncthreads();
    int s = bounds[0], e = bounds[1];
    int c = tid & 127, rgp = tid >> 7;
    float a = 0.f;
    for (int n = s + rgp; n < e; n += 2) a += x[(size_t)n * 128 + c];
    tmp[tid] = a;
    __syncthreads();
    if (tid < 128) xg[tid] = tmp[tid] + tmp[tid + 128];
    __syncthreads();
    float cntf = (float)(e - s);
    for (int j = tid; j < 1024; j += 256) {
        float o = cntf * bo[j];
        for (int cc = 0; cc < 128; cc++) o += xg[cc] * W[(size_t)cc * 1024 + j];
        out[(size_t)g * 1024 + j] = o;
    }
}

extern "C" void kernel_launch(void* const* d_in, const int* in_sizes, int n_in,
                              void* d_out, int out_size, void* d_ws, size_t ws_size,
                              hipStream_t stream) {
    const int N = in_sizes[0];
    const int E = in_sizes[2] / 2;
    const int NG = in_sizes[5] / CTXD;
    const int* at = (const int*)d_in[0];
    const float* pos = (const float*)d_in[1];
    const int* ei = (const int*)d_in[2];
    const int* batch = (const int*)d_in[4];
    const float* ctx = (const float*)d_in[5];
    const float* embW = (const float*)d_in[6];
    const float* embB = (const float*)d_in[7];
    const float* W1 = (const float*)d_in[8];
    const float* b1 = (const float*)d_in[9];
    const float* rg = (const float*)d_in[10];
    const float* rb = (const float*)d_in[11];
    const float* rm = (const float*)d_in[12];
    const float* rv = (const float*)d_in[13];
    const float* W2 = (const float*)d_in[14];
    const float* b2 = (const float*)d_in[15];
    const float* gatW = (const float*)d_in[16];
    const float* atts = (const float*)d_in[17];
    const float* attd = (const float*)d_in[18];
    const float* gbias = (const float*)d_in[19];
    const float* bg = (const float*)d_in[20];
    const float* bbb = (const float*)d_in[21];
    const float* bm = (const float*)d_in[22];
    const float* bv = (const float*)d_in[23];
    const float* outW = (const float*)d_in[24];
    const float* outb = (const float*)d_in[25];
    float* out = (float*)d_out;

    char* basep = (char*)d_ws;
    size_t off = 0;
    auto alloc = [&](size_t bytes) -> char* {
        char* p = basep + off;
        off = (off + bytes + 255) & ~(size_t)255;
        return p;
    };
    unsigned short* xc = (unsigned short*)alloc((size_t)N * INDIM * 2);
    float* x = (float*)alloc((size_t)N * 128 * 4);
    unsigned short* h = (unsigned short*)alloc((size_t)N * 128 * 2);
    unsigned short* xs = (unsigned short*)alloc((size_t)N * 512 * 2);
    float* a_src = (float*)alloc((size_t)N * 4 * 4);
    float* a_dst = (float*)alloc((size_t)N * 4 * 4);
    int* cnt = (int*)alloc((size_t)N * 4);
    int* rowptr = (int*)alloc((size_t)(N + 1) * 4);
    int* cursor = (int*)alloc((size_t)N * 4);
    int* csrc = (int*)alloc((size_t)(E + N) * 4);
    unsigned short* gatWt = (unsigned short*)alloc((size_t)NLAYERS * 512 * INDIM * 2);
    unsigned short* W2t = (unsigned short*)alloc((size_t)CTXD * 128 * 2);
    unsigned short* W1t = (unsigned short*)alloc((size_t)128 * KPAD * 2);
    (void)ws_size; (void)n_in; (void)out_size;

    // weight prep
    {
        dim3 b(32, 8);
        dim3 g1((512 + 31) / 32, (INDIM + 31) / 32, NLAYERS);
        k_tr<<<g1, b, 0, stream>>>(gatW, gatWt, INDIM, 512);
        dim3 g2((CTXD + 31) / 32, (128 + 31) / 32, 1);
        k_tr<<<g2, b, 0, stream>>>(W2, W2t, 128, CTXD);
        k_trW1<<<(128 * KPAD + 255) / 256, 256, 0, stream>>>(W1, W1t);
    }
    k_embed<<<(N * 128 + 255) / 256, 256, 0, stream>>>(at, embW, embB, x, xc, N);
    k_rbf_mfma<<<(N + 127) / 128, 256, 0, stream>>>(pos, W1t, b1, rg, rb, rm, rv, h, N);
    {
        dim3 g((N + 127) / 128, CTXD / 128);
        k_gemm<1><<<g, 256, 0, stream>>>(h, 128, N, W2t, 128, 128, xc, INDIM, batch, ctx, b2);
    }
    // CSR (dst-sorted incoming edges incl. self-loops)
    k_cnt_init<<<(N + 255) / 256, 256, 0, stream>>>(cnt, N);
    k_cnt<<<(E + 255) / 256, 256, 0, stream>>>(ei, E, cnt);
    k_scan<<<1, 1024, 0, stream>>>(cnt, rowptr, cursor, N);
    k_fill<<<(E + N + 255) / 256, 256, 0, stream>>>(ei, E, N, cursor, csrc);
    // GAT layers
    {
        dim3 g((N + 127) / 128, 512 / 128);
        for (int l = 0; l < NLAYERS; l++) {
            k_gemm<0><<<g, 256, 0, stream>>>(xc, INDIM, N, gatWt + (size_t)l * 512 * INDIM, INDIM,
                                             INDIM, xs, 512, nullptr, nullptr, nullptr);
            k_att<<<(N + 3) / 4, 256, 0, stream>>>(xs, atts + l * HEADS * 128, attd + l * HEADS * 128,
                                                   a_src, a_dst, N);
            k_agg<<<(N + 3) / 4, 256, 0, stream>>>(rowptr, csrc, a_src, a_dst, xs,
                                                   gbias + l * 128, bg + l * 128, bbb + l * 128,
                                                   bm + l * 128, bv + l * 128, x, xc, N);
        }
    }
    k_pool<<<NG, 256, 0, stream>>>(x, batch, outW, outb, out, N);
}

// Round 5
// 508.507 us; speedup vs baseline: 1.4768x; 1.3021x over previous
//
#include <hip/hip_runtime.h>
#include <hip/hip_bf16.h>
#include <cstdint>

constexpr int HIDDEN = 128, CTXD = 2048, HEADS = 4, NLAYERS = 3;
constexpr int KRBF = 720, KPAD = 736;  // 736 = 23 * 32
constexpr int KXH = 256;               // concat [x | h] K-dim

typedef __bf16 bf16x8 __attribute__((ext_vector_type(8)));
typedef float f32x4 __attribute__((ext_vector_type(4)));

static __device__ __forceinline__ unsigned short f2bf(float f) {
    union { float f; unsigned u; } v; v.f = f;
    unsigned r = v.u + 0x7fffu + ((v.u >> 16) & 1u);
    return (unsigned short)(r >> 16);
}
static __device__ __forceinline__ float bf2f(unsigned short s) {
    union { unsigned u; float f; } v; v.u = ((unsigned)s) << 16; return v.f;
}

// ---------------- weight transpose (f32 [B,R,C] -> bf16 [B,C,R]) ----------------
__global__ __launch_bounds__(256) void k_tr(const float* __restrict__ src,
                                            unsigned short* __restrict__ dst,
                                            int R, int C) {
    __shared__ unsigned short t[32][34];
    int b = blockIdx.z;
    int c0 = blockIdx.x * 32, r0 = blockIdx.y * 32;
    const float* s = src + (size_t)b * R * C;
    unsigned short* d = dst + (size_t)b * R * C;
    for (int rr = threadIdx.y; rr < 32; rr += 8) {
        int r = r0 + rr, c = c0 + threadIdx.x;
        unsigned short val = 0;
        if (r < R && c < C) val = f2bf(s[(size_t)r * C + c]);
        t[rr][threadIdx.x] = val;
    }
    __syncthreads();
    for (int rr = threadIdx.y; rr < 32; rr += 8) {
        int c = c0 + rr, r = r0 + threadIdx.x;
        if (c < C && r < R) d[(size_t)c * R + r] = t[threadIdx.x][rr];
    }
}

// ---------------- small elementwise prep kernels ----------------
__global__ __launch_bounds__(256) void k_w2bf(const float* __restrict__ W2,
                                              unsigned short* __restrict__ W2bf) {
    int i = blockIdx.x * 256 + threadIdx.x;
    if (i < 128 * CTXD) W2bf[i] = f2bf(W2[i]);
}
__global__ __launch_bounds__(256) void k_cpre(const float* __restrict__ ctx,
                                              const float* __restrict__ b2,
                                              unsigned short* __restrict__ cpre, int NG) {
    int i = blockIdx.x * 256 + threadIdx.x;
    if (i < NG * CTXD) cpre[i] = f2bf(ctx[i] + b2[i % CTXD]);
}
// Bc[l][o][0:128] = gatWt[l][o][0:128]  (Wx^T part)
__global__ __launch_bounds__(256) void k_bccopy(const unsigned short* __restrict__ gatWt,
                                                unsigned short* __restrict__ Bc) {
    int i = blockIdx.x * 256 + threadIdx.x;
    if (i >= NLAYERS * 512 * 128) return;
    int lo = i >> 7, k = i & 127;  // lo = l*512+o
    Bc[(size_t)lo * KXH + k] = gatWt[(size_t)lo * 2176 + k];
}

// ---------------- embedding gather ----------------
__global__ __launch_bounds__(256) void k_embed(const int* __restrict__ at,
                                               const float* __restrict__ W,
                                               const float* __restrict__ b,
                                               float* __restrict__ x,
                                               unsigned short* __restrict__ xh, int N) {
    int i = blockIdx.x * 256 + threadIdx.x;
    if (i >= N * HIDDEN) return;
    int n = i >> 7, c = i & 127;
    float v = W[(size_t)at[n] * HIDDEN + c] + b[c];
    x[i] = v;
    xh[(size_t)n * KXH + c] = f2bf(v);
}

// ---------------- fused RBF + Linear(720->128) via MFMA + BN + ReLU -> xh[:,128:256] ----------------
__global__ __launch_bounds__(256) void k_rbf_mfma(const float* __restrict__ pos,
                                                  const unsigned short* __restrict__ W1t,
                                                  const float* __restrict__ b1,
                                                  const float* __restrict__ g,
                                                  const float* __restrict__ bb,
                                                  const float* __restrict__ bm,
                                                  const float* __restrict__ bv,
                                                  unsigned short* __restrict__ xh, int N) {
    constexpr int LDT = 40;
    __shared__ unsigned short As[128 * LDT];
    __shared__ unsigned short Bs[128 * LDT];
    __shared__ float ps[128 * 3];
    const int tid = threadIdx.x;
    const int lane = tid & 63, wid = tid >> 6;
    const int nb = blockIdx.x * 128;
    for (int i = tid; i < 384; i += 256) {
        int n = nb + i / 3;
        ps[i] = (n < N) ? pos[(size_t)n * 3 + (i % 3)] : 1.0e9f;  // pad rows -> rbf = 0
    }
    __syncthreads();
    const int sr = tid >> 1, sk = (tid & 1) * 16;
    const int wr = (wid >> 1) * 64, wc = (wid & 1) * 64;
    const int fr = lane & 15, kg = lane >> 4;
    f32x4 acc[4][4];
#pragma unroll
    for (int i = 0; i < 4; i++)
#pragma unroll
        for (int j = 0; j < 4; j++)
#pragma unroll
            for (int r = 0; r < 4; r++) acc[i][j][r] = 0.f;
    const float p0 = ps[sr * 3], p1 = ps[sr * 3 + 1], p2 = ps[sr * 3 + 2];
    const unsigned short* bp = W1t + (size_t)sr * KPAD + sk;
    uint4 bv0 = *(const uint4*)bp, bv1 = *(const uint4*)(bp + 8);
    constexpr int NST = KPAD / 32;
    for (int ks = 0; ks < NST; ++ks) {
        unsigned short av[16];
#pragma unroll
        for (int j = 0; j < 16; j++) {
            int kglob = ks * 32 + sk + j;
            float v = 0.f;
            if (kglob < KRBF) {
                int d = kglob / 240, bin = kglob % 240;
                float mu = -30.f + (60.f / 239.f) * (float)bin;
                float p = (d == 0) ? p0 : ((d == 1) ? p1 : p2);
                float df = p - mu;
                v = __expf(-0.5f * df * df);
            }
            av[j] = f2bf(v);
        }
        __syncthreads();
        *(uint4*)&As[sr * LDT + sk] = *(const uint4*)&av[0];
        *(uint4*)&As[sr * LDT + sk + 8] = *(const uint4*)&av[8];
        *(uint4*)&Bs[sr * LDT + sk] = bv0;
        *(uint4*)&Bs[sr * LDT + sk + 8] = bv1;
        __syncthreads();
        if (ks + 1 < NST) {
            const unsigned short* bp2 = W1t + (size_t)sr * KPAD + (ks + 1) * 32 + sk;
            bv0 = *(const uint4*)bp2;
            bv1 = *(const uint4*)(bp2 + 8);
        }
        bf16x8 afr[4], bfr[4];
#pragma unroll
        for (int i = 0; i < 4; i++) {
            afr[i] = *reinterpret_cast<const bf16x8*>(&As[(wr + i * 16 + fr) * LDT + kg * 8]);
            bfr[i] = *reinterpret_cast<const bf16x8*>(&Bs[(wc + i * 16 + fr) * LDT + kg * 8]);
        }
#pragma unroll
        for (int i = 0; i < 4; i++)
#pragma unroll
            for (int j = 0; j < 4; j++)
                acc[i][j] = __builtin_amdgcn_mfma_f32_16x16x32_bf16(afr[i], bfr[j], acc[i][j], 0, 0, 0);
    }
    const int rg = lane >> 4;
#pragma unroll
    for (int i = 0; i < 4; i++) {
#pragma unroll
        for (int j = 0; j < 4; j++) {
            int col = wc + j * 16 + fr;
            float sc = g[col] * rsqrtf(bv[col] + 1e-5f);
            float sh = bb[col] - bm[col] * sc;
            float bc = b1[col];
#pragma unroll
            for (int r = 0; r < 4; r++) {
                int row = nb + wr + i * 16 + rg * 4 + r;
                if (row < N) {
                    float y = (acc[i][j][r] + bc) * sc + sh;
                    y = fmaxf(y, 0.f);
                    xh[(size_t)row * KXH + 128 + col] = f2bf(y);
                }
            }
        }
    }
}

// ---------------- W1 transpose to bf16 [128][KPAD], zero-padded K ----------------
__global__ __launch_bounds__(256) void k_trW1(const float* __restrict__ W1,
                                              unsigned short* __restrict__ W1t) {
    int i = blockIdx.x * 256 + threadIdx.x;
    if (i >= 128 * KPAD) return;
    int c = i / KPAD, k = i % KPAD;
    unsigned short v = 0;
    if (k < KRBF) v = f2bf(W1[(size_t)k * 128 + c]);
    W1t[i] = v;
}

// ---------------- bf16 MFMA GEMM: C[M,N] = A[M,K] @ Bt[N,K]^T, strided-batch over z --------
// MODE 0: bf16 out. MODE 2: f32 out. MODE 3: bf16 out + cw[batch[row]*512+col].
template <int MODE>
__global__ __launch_bounds__(256) void k_gemm(const unsigned short* __restrict__ A, int lda, int M,
                                              const unsigned short* __restrict__ Bt, int ldb,
                                              int K,
                                              void* __restrict__ Cout, int ldc,
                                              const int* __restrict__ batch,
                                              const float* __restrict__ cw,
                                              long sA, long sB, long sC) {
    constexpr int LDT = 40;  // 32 + 8 pad shorts
    __shared__ unsigned short As[128 * LDT];
    __shared__ unsigned short Bs[128 * LDT];
    const int z = blockIdx.z;
    A += (size_t)z * sA;
    Bt += (size_t)z * sB;
    const int tid = threadIdx.x;
    const int lane = tid & 63, wid = tid >> 6;
    const int m0 = blockIdx.x * 128, n0 = blockIdx.y * 128;
    const int wr = (wid >> 1) * 64, wc = (wid & 1) * 64;
    const int sr = tid >> 1, sk = (tid & 1) * 16;
    f32x4 acc[4][4];
#pragma unroll
    for (int i = 0; i < 4; i++)
#pragma unroll
        for (int j = 0; j < 4; j++)
#pragma unroll
            for (int r = 0; r < 4; r++) acc[i][j][r] = 0.f;
    const int nst = K / 32;
    const int arow = min(m0 + sr, M - 1);
    const unsigned short* ap = A + (size_t)arow * lda + sk;
    const unsigned short* bp = Bt + (size_t)(n0 + sr) * ldb + sk;
    uint4 av0 = *(const uint4*)ap, av1 = *(const uint4*)(ap + 8);
    uint4 bv0 = *(const uint4*)bp, bv1 = *(const uint4*)(bp + 8);
    const int fr = lane & 15, kg = lane >> 4;
    for (int ks = 0; ks < nst; ++ks) {
        __syncthreads();
        *(uint4*)&As[sr * LDT + sk] = av0;
        *(uint4*)&As[sr * LDT + sk + 8] = av1;
        *(uint4*)&Bs[sr * LDT + sk] = bv0;
        *(uint4*)&Bs[sr * LDT + sk + 8] = bv1;
        __syncthreads();
        if (ks + 1 < nst) {  // prefetch next K-step into regs, overlaps with MFMA below
            const unsigned short* ap2 = A + (size_t)arow * lda + (ks + 1) * 32 + sk;
            const unsigned short* bp2 = Bt + (size_t)(n0 + sr) * ldb + (ks + 1) * 32 + sk;
            av0 = *(const uint4*)ap2; av1 = *(const uint4*)(ap2 + 8);
            bv0 = *(const uint4*)bp2; bv1 = *(const uint4*)(bp2 + 8);
        }
        bf16x8 afr[4], bfr[4];
#pragma unroll
        for (int i = 0; i < 4; i++) {
            afr[i] = *reinterpret_cast<const bf16x8*>(&As[(wr + i * 16 + fr) * LDT + kg * 8]);
            bfr[i] = *reinterpret_cast<const bf16x8*>(&Bs[(wc + i * 16 + fr) * LDT + kg * 8]);
        }
#pragma unroll
        for (int i = 0; i < 4; i++)
#pragma unroll
            for (int j = 0; j < 4; j++)
                acc[i][j] = __builtin_amdgcn_mfma_f32_16x16x32_bf16(afr[i], bfr[j], acc[i][j], 0, 0, 0);
    }
    const int rg = lane >> 4;  // C/D: col = lane&15, row = (lane>>4)*4 + reg
#pragma unroll
    for (int i = 0; i < 4; i++) {
#pragma unroll
        for (int j = 0; j < 4; j++) {
            int col = n0 + wc + j * 16 + fr;
#pragma unroll
            for (int r = 0; r < 4; r++) {
                int row = m0 + wr + i * 16 + rg * 4 + r;
                if (row < M) {
                    float vv = acc[i][j][r];
                    if (MODE == 2) {
                        ((float*)Cout)[(size_t)z * sC + (size_t)row * ldc + col] = vv;
                    } else if (MODE == 3) {
                        vv += cw[(size_t)batch[row] * 512 + col];
                        ((unsigned short*)Cout)[(size_t)row * ldc + col] = f2bf(vv);
                    } else {
                        ((unsigned short*)Cout)[(size_t)z * sC + (size_t)row * ldc + col] = f2bf(vv);
                    }
                }
            }
        }
    }
}

// ---------------- attention logits: a_src/a_dst [N,4] ----------------
__global__ __launch_bounds__(256) void k_att(const unsigned short* __restrict__ xs,
                                             const float* __restrict__ att_s,
                                             const float* __restrict__ att_d,
                                             float* __restrict__ a_src,
                                             float* __restrict__ a_dst, int N) {
    int tid = threadIdx.x, lane = tid & 63, wid = tid >> 6;
    int n = blockIdx.x * 4 + wid;
    if (n >= N) return;
    int h = lane >> 4, c0 = (lane & 15) * 8;
    uint4 raw = *(const uint4*)(xs + (size_t)n * 512 + h * 128 + c0);
    const unsigned short* rs = (const unsigned short*)&raw;
    float ss = 0.f, sd = 0.f;
#pragma unroll
    for (int j = 0; j < 8; j++) {
        float xv = bf2f(rs[j]);
        ss += xv * att_s[h * 128 + c0 + j];
        sd += xv * att_d[h * 128 + c0 + j];
    }
#pragma unroll
    for (int d = 1; d < 16; d <<= 1) {
        ss += __shfl_xor(ss, d);
        sd += __shfl_xor(sd, d);
    }
    if ((lane & 15) == 0) {
        a_src[n * 4 + h] = ss;
        a_dst[n * 4 + h] = sd;
    }
}

// ---------------- CSR build ----------------
__global__ void k_cnt_init(int* cnt, int N) {
    int i = blockIdx.x * 256 + threadIdx.x;
    if (i < N) cnt[i] = 1;  // self-loop
}
__global__ void k_cnt(const int* __restrict__ ei, int E, int* cnt) {
    int i = blockIdx.x * 256 + threadIdx.x;
    if (i < E) atomicAdd(&cnt[ei[E + i]], 1);
}
__global__ __launch_bounds__(1024) void k_scan(const int* __restrict__ cnt, int* __restrict__ rowptr,
                                               int* __restrict__ cursor, int n) {
    __shared__ int wsum[16];
    __shared__ int carry;
    int tid = threadIdx.x, lane = tid & 63, wid = tid >> 6;
    if (tid == 0) carry = 0;
    __syncthreads();
    for (int basei = 0; basei < n; basei += 1024) {
        int i = basei + tid;
        int v = (i < n) ? cnt[i] : 0;
        int s = v;
#pragma unroll
        for (int d = 1; d < 64; d <<= 1) {
            int t = __shfl_up(s, (unsigned)d);
            if (lane >= d) s += t;
        }
        if (lane == 63) wsum[wid] = s;
        __syncthreads();
        if (wid == 0 && lane < 16) {
            int ws = wsum[lane]; int t = ws;
#pragma unroll
            for (int d = 1; d < 16; d <<= 1) {
                int u = __shfl_up(t, (unsigned)d);
                if (lane >= d) t += u;
            }
            wsum[lane] = t - ws;  // exclusive wave offsets
        }
        __syncthreads();
        int excl = carry + wsum[wid] + (s - v);
        if (i < n) { rowptr[i] = excl; cursor[i] = excl; }
        __syncthreads();
        if (tid == 1023) carry += wsum[15] + s;
        __syncthreads();
    }
    if (tid == 0) rowptr[n] = carry;
}
__global__ void k_fill(const int* __restrict__ ei, int E, int N, int* cursor, int* csrc) {
    int i = blockIdx.x * 256 + threadIdx.x;
    if (i >= E + N) return;
    int s, d;
    if (i < E) { s = ei[i]; d = ei[E + i]; }
    else { s = i - E; d = s; }
    int slot = atomicAdd(&cursor[d], 1);
    csrc[slot] = s;
}

// ---------------- GAT aggregation + softmax + BN + GELU + residual ----------------
__global__ __launch_bounds__(256) void k_agg(const int* __restrict__ rowptr,
                                             const int* __restrict__ csrc,
                                             const float* __restrict__ asrc,
                                             const float* __restrict__ adstv,
                                             const unsigned short* __restrict__ xs,
                                             const float* __restrict__ gbias,
                                             const float* __restrict__ bg,
                                             const float* __restrict__ bb,
                                             const float* __restrict__ bm,
                                             const float* __restrict__ bv,
                                             float* __restrict__ x,
                                             unsigned short* __restrict__ xh, int N) {
    int tid = threadIdx.x, lane = tid & 63, wid = tid >> 6;
    int n = blockIdx.x * 4 + wid;
    if (n >= N) return;
    int beg = rowptr[n], end = rowptr[n + 1];
    float ad[4];
#pragma unroll
    for (int hh = 0; hh < 4; hh++) ad[hh] = adstv[n * 4 + hh];
    // pass 1: per-head max
    float mx[4] = {-1e30f, -1e30f, -1e30f, -1e30f};
    for (int e = beg + lane; e < end; e += 64) {
        int s = csrc[e];
#pragma unroll
        for (int hh = 0; hh < 4; hh++) {
            float a = asrc[s * 4 + hh] + ad[hh];
            a = a > 0.f ? a : 0.2f * a;
            mx[hh] = fmaxf(mx[hh], a);
        }
    }
#pragma unroll
    for (int d = 1; d < 64; d <<= 1)
#pragma unroll
        for (int hh = 0; hh < 4; hh++) mx[hh] = fmaxf(mx[hh], __shfl_xor(mx[hh], d));
    // pass 2: denom
    float sm[4] = {0.f, 0.f, 0.f, 0.f};
    for (int e = beg + lane; e < end; e += 64) {
        int s = csrc[e];
#pragma unroll
        for (int hh = 0; hh < 4; hh++) {
            float a = asrc[s * 4 + hh] + ad[hh];
            a = a > 0.f ? a : 0.2f * a;
            sm[hh] += __expf(a - mx[hh]);
        }
    }
#pragma unroll
    for (int d = 1; d < 64; d <<= 1)
#pragma unroll
        for (int hh = 0; hh < 4; hh++) sm[hh] += __shfl_xor(sm[hh], d);
    // pass 3: weighted message accumulation. lane covers head h, channels c0..c0+7
    int h = lane >> 4, c0 = (lane & 15) * 8;
    float am = mx[h], iv = 1.f / fmaxf(sm[h], 1e-16f), adh = ad[h];
    float acc[8];
#pragma unroll
    for (int j = 0; j < 8; j++) acc[j] = 0.f;
    for (int e = beg; e < end; e++) {
        int s = csrc[e];
        float a = asrc[s * 4 + h] + adh;
        a = a > 0.f ? a : 0.2f * a;
        float w = __expf(a - am) * iv;
        uint4 raw = *(const uint4*)(xs + (size_t)s * 512 + h * 128 + c0);
        const unsigned short* rs = (const unsigned short*)&raw;
#pragma unroll
        for (int j = 0; j < 8; j++) acc[j] += w * bf2f(rs[j]);
    }
    // head mean across lanes (h = lane>>4)
#pragma unroll
    for (int j = 0; j < 8; j++) {
        acc[j] += __shfl_xor(acc[j], 16);
        acc[j] += __shfl_xor(acc[j], 32);
    }
    if (lane < 16) {
#pragma unroll
        for (int j = 0; j < 8; j++) {
            int c = c0 + j;
            float t = acc[j] * 0.25f + gbias[c];
            float sc = bg[c] * rsqrtf(bv[c] + 1e-5f);
            float y = (t - bm[c]) * sc + bb[c];
            float ge = 0.5f * y * (1.f + erff(y * 0.70710678118f));
            float xn = x[(size_t)n * 128 + c] + ge;
            x[(size_t)n * 128 + c] = xn;
            xh[(size_t)n * KXH + c] = f2bf(xn);
        }
    }
}

// ---------------- fused pool + final linear ----------------
__global__ __launch_bounds__(256) void k_pool(const float* __restrict__ x,
                                              const int* __restrict__ batch,
                                              const float* __restrict__ W,
                                              const float* __restrict__ bo,
                                              float* __restrict__ out, int N) {
    __shared__ float xg[128];
    __shared__ float tmp[256];
    __shared__ int bounds[2];
    int g = blockIdx.x, tid = threadIdx.x;
    if (tid < 2) {
        int key = g + tid, lo = 0, hi = N;
        while (lo < hi) { int mid = (lo + hi) >> 1; if (batch[mid] < key) lo = mid + 1; else hi = mid; }
        bounds[tid] = lo;
    }
    __syncthreads();
    int s = bounds[0], e = bounds[1];
    int c = tid & 127, rgp = tid >> 7;
    float a = 0.f;
    for (int n = s + rgp; n < e; n += 2) a += x[(size_t)n * 128 + c];
    tmp[tid] = a;
    __syncthreads();
    if (tid < 128) xg[tid] = tmp[tid] + tmp[tid + 128];
    __syncthreads();
    float cntf = (float)(e - s);
    for (int j = tid; j < 1024; j += 256) {
        float o = cntf * bo[j];
        for (int cc = 0; cc < 128; cc++) o += xg[cc] * W[(size_t)cc * 1024 + j];
        out[(size_t)g * 1024 + j] = o;
    }
}

extern "C" void kernel_launch(void* const* d_in, const int* in_sizes, int n_in,
                              void* d_out, int out_size, void* d_ws, size_t ws_size,
                              hipStream_t stream) {
    const int N = in_sizes[0];
    const int E = in_sizes[2] / 2;
    const int NG = in_sizes[5] / CTXD;
    const int* at = (const int*)d_in[0];
    const float* pos = (const float*)d_in[1];
    const int* ei = (const int*)d_in[2];
    const int* batch = (const int*)d_in[4];
    const float* ctx = (const float*)d_in[5];
    const float* embW = (const float*)d_in[6];
    const float* embB = (const float*)d_in[7];
    const float* W1 = (const float*)d_in[8];
    const float* b1 = (const float*)d_in[9];
    const float* rg = (const float*)d_in[10];
    const float* rb = (const float*)d_in[11];
    const float* rm = (const float*)d_in[12];
    const float* rv = (const float*)d_in[13];
    const float* W2 = (const float*)d_in[14];
    const float* b2 = (const float*)d_in[15];
    const float* gatW = (const float*)d_in[16];
    const float* atts = (const float*)d_in[17];
    const float* attd = (const float*)d_in[18];
    const float* gbias = (const float*)d_in[19];
    const float* bg = (const float*)d_in[20];
    const float* bbb = (const float*)d_in[21];
    const float* bm = (const float*)d_in[22];
    const float* bv = (const float*)d_in[23];
    const float* outW = (const float*)d_in[24];
    const float* outb = (const float*)d_in[25];
    float* out = (float*)d_out;

    char* basep = (char*)d_ws;
    size_t off = 0;
    auto alloc = [&](size_t bytes) -> char* {
        char* p = basep + off;
        off = (off + bytes + 255) & ~(size_t)255;
        return p;
    };
    unsigned short* xh = (unsigned short*)alloc((size_t)N * KXH * 2);
    float* x = (float*)alloc((size_t)N * 128 * 4);
    unsigned short* xs = (unsigned short*)alloc((size_t)N * 512 * 2);
    float* a_src = (float*)alloc((size_t)N * 4 * 4);
    float* a_dst = (float*)alloc((size_t)N * 4 * 4);
    int* cnt = (int*)alloc((size_t)N * 4);
    int* rowptr = (int*)alloc((size_t)(N + 1) * 4);
    int* cursor = (int*)alloc((size_t)N * 4);
    int* csrc = (int*)alloc((size_t)(E + N) * 4);
    unsigned short* gatWt = (unsigned short*)alloc((size_t)NLAYERS * 512 * 2176 * 2);
    unsigned short* W1t = (unsigned short*)alloc((size_t)128 * KPAD * 2);
    unsigned short* W2bf = (unsigned short*)alloc((size_t)128 * CTXD * 2);
    unsigned short* cpre = (unsigned short*)alloc((size_t)NG * CTXD * 2);
    unsigned short* Bc = (unsigned short*)alloc((size_t)NLAYERS * 512 * KXH * 2);
    float* cW = (float*)alloc((size_t)NLAYERS * NG * 512 * 4);
    (void)ws_size; (void)n_in; (void)out_size;

    // ---- weight prep ----
    {
        dim3 b(32, 8);
        dim3 g1((512 + 31) / 32, (2176 + 31) / 32, NLAYERS);
        k_tr<<<g1, b, 0, stream>>>(gatW, gatWt, 2176, 512);
        k_trW1<<<(128 * KPAD + 255) / 256, 256, 0, stream>>>(W1, W1t);
        k_w2bf<<<(128 * CTXD + 255) / 256, 256, 0, stream>>>(W2, W2bf);
        k_cpre<<<(NG * CTXD + 255) / 256, 256, 0, stream>>>(ctx, b2, cpre, NG);
        k_bccopy<<<(NLAYERS * 512 * 128 + 255) / 256, 256, 0, stream>>>(gatWt, Bc);
        // Bc[l][:,128:256] = (W2 @ Wc[l])^T = gatWt[l][:,128:2176] @ W2bf^T, M=512,N=128,K=2048
        dim3 gm(4, 1, NLAYERS);
        k_gemm<0><<<gm, 256, 0, stream>>>(gatWt + 128, 2176, 512, W2bf, CTXD, CTXD,
                                          Bc + 128, KXH, nullptr, nullptr,
                                          (long)512 * 2176, 0, (long)512 * KXH);
        // cW[l] = cpre @ Wc[l]: M=NG, N=512, K=2048, f32 out
        dim3 gc(1, 4, NLAYERS);
        k_gemm<2><<<gc, 256, 0, stream>>>(cpre, CTXD, NG, gatWt + 128, 2176, CTXD,
                                          cW, 512, nullptr, nullptr,
                                          0, (long)512 * 2176, (long)NG * 512);
    }
    // ---- node features ----
    k_embed<<<(N * 128 + 255) / 256, 256, 0, stream>>>(at, embW, embB, x, xh, N);
    k_rbf_mfma<<<(N + 127) / 128, 256, 0, stream>>>(pos, W1t, b1, rg, rb, rm, rv, xh, N);
    // ---- CSR (dst-sorted incoming edges incl. self-loops) ----
    k_cnt_init<<<(N + 255) / 256, 256, 0, stream>>>(cnt, N);
    k_cnt<<<(E + 255) / 256, 256, 0, stream>>>(ei, E, cnt);
    k_scan<<<1, 1024, 0, stream>>>(cnt, rowptr, cursor, N);
    k_fill<<<(E + N + 255) / 256, 256, 0, stream>>>(ei, E, N, cursor, csrc);
    // ---- GAT layers ----
    {
        dim3 g((N + 127) / 128, 4, 1);
        for (int l = 0; l < NLAYERS; l++) {
            k_gemm<3><<<g, 256, 0, stream>>>(xh, KXH, N, Bc + (size_t)l * 512 * KXH, KXH, KXH,
                                             xs, 512, batch, cW + (size_t)l * NG * 512,
                                             0, 0, 0);
            k_att<<<(N + 3) / 4, 256, 0, stream>>>(xs, atts + l * HEADS * 128, attd + l * HEADS * 128,
                                                   a_src, a_dst, N);
            k_agg<<<(N + 3) / 4, 256, 0, stream>>>(rowptr, csrc, a_src, a_dst, xs,
                                                   gbias + l * 128, bg + l * 128, bbb + l * 128,
                                                   bm + l * 128, bv + l * 128, x, xh, N);
        }
    }
    k_pool<<<NG, 256, 0, stream>>>(x, batch, outW, outb, out, N);
}

// Round 6
// 472.146 us; speedup vs baseline: 1.5906x; 1.0770x over previous
//
#include <hip/hip_runtime.h>
#include <hip/hip_bf16.h>
#include <cstdint>

constexpr int HIDDEN = 128, CTXD = 2048, HEADS = 4, NLAYERS = 3;
constexpr int KRBF = 720, KPAD = 736;  // 736 = 23 * 32
constexpr int KXH = 256;               // concat [x | h] K-dim

typedef __bf16 bf16x8 __attribute__((ext_vector_type(8)));
typedef float f32x4 __attribute__((ext_vector_type(4)));

static __device__ __forceinline__ unsigned short f2bf(float f) {
    union { float f; unsigned u; } v; v.f = f;
    unsigned r = v.u + 0x7fffu + ((v.u >> 16) & 1u);
    return (unsigned short)(r >> 16);
}
static __device__ __forceinline__ float bf2f(unsigned short s) {
    union { unsigned u; float f; } v; v.u = ((unsigned)s) << 16; return v.f;
}

// ---------------- weight transpose (f32 [B,R,C] -> bf16 [B,C,R]) ----------------
__global__ __launch_bounds__(256) void k_tr(const float* __restrict__ src,
                                            unsigned short* __restrict__ dst,
                                            int R, int C) {
    __shared__ unsigned short t[32][34];
    int b = blockIdx.z;
    int c0 = blockIdx.x * 32, r0 = blockIdx.y * 32;
    const float* s = src + (size_t)b * R * C;
    unsigned short* d = dst + (size_t)b * R * C;
    for (int rr = threadIdx.y; rr < 32; rr += 8) {
        int r = r0 + rr, c = c0 + threadIdx.x;
        unsigned short val = 0;
        if (r < R && c < C) val = f2bf(s[(size_t)r * C + c]);
        t[rr][threadIdx.x] = val;
    }
    __syncthreads();
    for (int rr = threadIdx.y; rr < 32; rr += 8) {
        int c = c0 + rr, r = r0 + threadIdx.x;
        if (c < C && r < R) d[(size_t)c * R + r] = t[threadIdx.x][rr];
    }
}

// ---------------- small elementwise prep kernels ----------------
__global__ __launch_bounds__(256) void k_w2bf(const float* __restrict__ W2,
                                              unsigned short* __restrict__ W2bf) {
    int i = blockIdx.x * 256 + threadIdx.x;
    if (i < 128 * CTXD) W2bf[i] = f2bf(W2[i]);
}
__global__ __launch_bounds__(256) void k_cpre(const float* __restrict__ ctx,
                                              const float* __restrict__ b2,
                                              unsigned short* __restrict__ cpre, int NG) {
    int i = blockIdx.x * 256 + threadIdx.x;
    if (i < NG * CTXD) cpre[i] = f2bf(ctx[i] + b2[i % CTXD]);
}
// Bc[l][o][0:128] = gatWt[l][o][0:128]  (Wx^T part)
__global__ __launch_bounds__(256) void k_bccopy(const unsigned short* __restrict__ gatWt,
                                                unsigned short* __restrict__ Bc) {
    int i = blockIdx.x * 256 + threadIdx.x;
    if (i >= NLAYERS * 512 * 128) return;
    int lo = i >> 7, k = i & 127;  // lo = l*512+o
    Bc[(size_t)lo * KXH + k] = gatWt[(size_t)lo * 2176 + k];
}

// ---------------- W1 transpose to bf16 [128][KPAD], zero-padded K ----------------
__global__ __launch_bounds__(256) void k_trW1(const float* __restrict__ W1,
                                              unsigned short* __restrict__ W1t) {
    int i = blockIdx.x * 256 + threadIdx.x;
    if (i >= 128 * KPAD) return;
    int c = i / KPAD, k = i % KPAD;
    unsigned short v = 0;
    if (k < KRBF) v = f2bf(W1[(size_t)k * 128 + c]);
    W1t[i] = v;
}

// ---------------- embedding gather ----------------
__global__ __launch_bounds__(256) void k_embed(const int* __restrict__ at,
                                               const float* __restrict__ W,
                                               const float* __restrict__ b,
                                               float* __restrict__ x,
                                               unsigned short* __restrict__ xh, int N) {
    int i = blockIdx.x * 256 + threadIdx.x;
    if (i >= N * HIDDEN) return;
    int n = i >> 7, c = i & 127;
    float v = W[(size_t)at[n] * HIDDEN + c] + b[c];
    x[i] = v;
    xh[(size_t)n * KXH + c] = f2bf(v);
}

// ---------------- fused RBF + Linear(720->128) via MFMA + BN + ReLU -> xh[:,128:256] ----------------
__global__ __launch_bounds__(256) void k_rbf_mfma(const float* __restrict__ pos,
                                                  const unsigned short* __restrict__ W1t,
                                                  const float* __restrict__ b1,
                                                  const float* __restrict__ g,
                                                  const float* __restrict__ bb,
                                                  const float* __restrict__ bm,
                                                  const float* __restrict__ bv,
                                                  unsigned short* __restrict__ xh, int N) {
    constexpr int LDT = 40;
    __shared__ unsigned short As[128 * LDT];
    __shared__ unsigned short Bs[128 * LDT];
    __shared__ float ps[128 * 3];
    const int tid = threadIdx.x;
    const int lane = tid & 63, wid = tid >> 6;
    const int nb = blockIdx.x * 128;
    for (int i = tid; i < 384; i += 256) {
        int n = nb + i / 3;
        ps[i] = (n < N) ? pos[(size_t)n * 3 + (i % 3)] : 1.0e9f;  // pad rows -> rbf = 0
    }
    __syncthreads();
    const int sr = tid >> 1, sk = (tid & 1) * 16;
    const int wr = (wid >> 1) * 64, wc = (wid & 1) * 64;
    const int fr = lane & 15, kg = lane >> 4;
    f32x4 acc[4][4];
#pragma unroll
    for (int i = 0; i < 4; i++)
#pragma unroll
        for (int j = 0; j < 4; j++)
#pragma unroll
            for (int r = 0; r < 4; r++) acc[i][j][r] = 0.f;
    const float p0 = ps[sr * 3], p1 = ps[sr * 3 + 1], p2 = ps[sr * 3 + 2];
    const unsigned short* bp = W1t + (size_t)sr * KPAD + sk;
    uint4 bv0 = *(const uint4*)bp, bv1 = *(const uint4*)(bp + 8);
    constexpr int NST = KPAD / 32;
    for (int ks = 0; ks < NST; ++ks) {
        unsigned short av[16];
#pragma unroll
        for (int j = 0; j < 16; j++) {
            int kglob = ks * 32 + sk + j;
            float v = 0.f;
            if (kglob < KRBF) {
                int d = kglob / 240, bin = kglob % 240;
                float mu = -30.f + (60.f / 239.f) * (float)bin;
                float p = (d == 0) ? p0 : ((d == 1) ? p1 : p2);
                float df = p - mu;
                v = __expf(-0.5f * df * df);
            }
            av[j] = f2bf(v);
        }
        __syncthreads();
        *(uint4*)&As[sr * LDT + sk] = *(const uint4*)&av[0];
        *(uint4*)&As[sr * LDT + sk + 8] = *(const uint4*)&av[8];
        *(uint4*)&Bs[sr * LDT + sk] = bv0;
        *(uint4*)&Bs[sr * LDT + sk + 8] = bv1;
        __syncthreads();
        if (ks + 1 < NST) {
            const unsigned short* bp2 = W1t + (size_t)sr * KPAD + (ks + 1) * 32 + sk;
            bv0 = *(const uint4*)bp2;
            bv1 = *(const uint4*)(bp2 + 8);
        }
        bf16x8 afr[4], bfr[4];
#pragma unroll
        for (int i = 0; i < 4; i++) {
            afr[i] = *reinterpret_cast<const bf16x8*>(&As[(wr + i * 16 + fr) * LDT + kg * 8]);
            bfr[i] = *reinterpret_cast<const bf16x8*>(&Bs[(wc + i * 16 + fr) * LDT + kg * 8]);
        }
#pragma unroll
        for (int i = 0; i < 4; i++)
#pragma unroll
            for (int j = 0; j < 4; j++)
                acc[i][j] = __builtin_amdgcn_mfma_f32_16x16x32_bf16(afr[i], bfr[j], acc[i][j], 0, 0, 0);
    }
    const int rg = lane >> 4;
#pragma unroll
    for (int i = 0; i < 4; i++) {
#pragma unroll
        for (int j = 0; j < 4; j++) {
            int col = wc + j * 16 + fr;
            float sc = g[col] * rsqrtf(bv[col] + 1e-5f);
            float sh = bb[col] - bm[col] * sc;
            float bc = b1[col];
#pragma unroll
            for (int r = 0; r < 4; r++) {
                int row = nb + wr + i * 16 + rg * 4 + r;
                if (row < N) {
                    float y = (acc[i][j][r] + bc) * sc + sh;
                    y = fmaxf(y, 0.f);
                    xh[(size_t)row * KXH + 128 + col] = f2bf(y);
                }
            }
        }
    }
}

// ---------------- shared MFMA GEMM core: C[M,N] = A[M,K] @ Bt[N,K]^T ----------------
// MODE 0: bf16 out. MODE 2: f32 out. MODE 3: bf16 out + cw[batch[row]*512+col].
template <int MODE>
__device__ __forceinline__ void gemm_core(unsigned short* As, unsigned short* Bs,
                                          const unsigned short* __restrict__ A, int lda, int M,
                                          const unsigned short* __restrict__ Bt, int ldb, int K,
                                          void* __restrict__ Cout, int ldc,
                                          const int* __restrict__ batch,
                                          const float* __restrict__ cw,
                                          int m0, int n0) {
    constexpr int LDT = 40;
    const int tid = threadIdx.x;
    const int lane = tid & 63, wid = tid >> 6;
    const int wr = (wid >> 1) * 64, wc = (wid & 1) * 64;
    const int sr = tid >> 1, sk = (tid & 1) * 16;
    f32x4 acc[4][4];
#pragma unroll
    for (int i = 0; i < 4; i++)
#pragma unroll
        for (int j = 0; j < 4; j++)
#pragma unroll
            for (int r = 0; r < 4; r++) acc[i][j][r] = 0.f;
    const int nst = K / 32;
    const int arow = min(m0 + sr, M - 1);
    const unsigned short* ap = A + (size_t)arow * lda + sk;
    const unsigned short* bp = Bt + (size_t)(n0 + sr) * ldb + sk;
    uint4 av0 = *(const uint4*)ap, av1 = *(const uint4*)(ap + 8);
    uint4 bv0 = *(const uint4*)bp, bv1 = *(const uint4*)(bp + 8);
    const int fr = lane & 15, kg = lane >> 4;
    for (int ks = 0; ks < nst; ++ks) {
        __syncthreads();
        *(uint4*)&As[sr * LDT + sk] = av0;
        *(uint4*)&As[sr * LDT + sk + 8] = av1;
        *(uint4*)&Bs[sr * LDT + sk] = bv0;
        *(uint4*)&Bs[sr * LDT + sk + 8] = bv1;
        __syncthreads();
        if (ks + 1 < nst) {  // prefetch next K-step into regs, overlaps with MFMA below
            const unsigned short* ap2 = A + (size_t)arow * lda + (ks + 1) * 32 + sk;
            const unsigned short* bp2 = Bt + (size_t)(n0 + sr) * ldb + (ks + 1) * 32 + sk;
            av0 = *(const uint4*)ap2; av1 = *(const uint4*)(ap2 + 8);
            bv0 = *(const uint4*)bp2; bv1 = *(const uint4*)(bp2 + 8);
        }
        bf16x8 afr[4], bfr[4];
#pragma unroll
        for (int i = 0; i < 4; i++) {
            afr[i] = *reinterpret_cast<const bf16x8*>(&As[(wr + i * 16 + fr) * LDT + kg * 8]);
            bfr[i] = *reinterpret_cast<const bf16x8*>(&Bs[(wc + i * 16 + fr) * LDT + kg * 8]);
        }
#pragma unroll
        for (int i = 0; i < 4; i++)
#pragma unroll
            for (int j = 0; j < 4; j++)
                acc[i][j] = __builtin_amdgcn_mfma_f32_16x16x32_bf16(afr[i], bfr[j], acc[i][j], 0, 0, 0);
    }
    const int rg = lane >> 4;  // C/D: col = lane&15, row = (lane>>4)*4 + reg
#pragma unroll
    for (int i = 0; i < 4; i++) {
#pragma unroll
        for (int j = 0; j < 4; j++) {
            int col = n0 + wc + j * 16 + fr;
#pragma unroll
            for (int r = 0; r < 4; r++) {
                int row = m0 + wr + i * 16 + rg * 4 + r;
                if (row < M) {
                    float vv = acc[i][j][r];
                    if (MODE == 2) {
                        ((float*)Cout)[(size_t)row * ldc + col] = vv;
                    } else if (MODE == 3) {
                        vv += cw[(size_t)batch[row] * 512 + col];
                        ((unsigned short*)Cout)[(size_t)row * ldc + col] = f2bf(vv);
                    } else {
                        ((unsigned short*)Cout)[(size_t)row * ldc + col] = f2bf(vv);
                    }
                }
            }
        }
    }
}

// GAT per-layer node GEMM (MODE 3)
__global__ __launch_bounds__(256) void k_gemm3(const unsigned short* __restrict__ A, int M,
                                               const unsigned short* __restrict__ Bt,
                                               unsigned short* __restrict__ C,
                                               const int* __restrict__ batch,
                                               const float* __restrict__ cw) {
    constexpr int LDT = 40;
    __shared__ unsigned short As[128 * LDT];
    __shared__ unsigned short Bs[128 * LDT];
    gemm_core<3>(As, Bs, A, KXH, M, Bt, KXH, KXH, C, 512, batch, cw,
                 blockIdx.x * 128, blockIdx.y * 128);
}

// merged weight-prep GEMMs: z<3 -> Bc[l][:,128:256] = Wc[l]^T @ W2^T; z>=3 -> cW[l] = cpre @ Wc[l]
__global__ __launch_bounds__(256) void k_prep(const unsigned short* __restrict__ gatWt,
                                              const unsigned short* __restrict__ W2bf,
                                              const unsigned short* __restrict__ cpre,
                                              unsigned short* __restrict__ Bc,
                                              float* __restrict__ cW, int NG) {
    constexpr int LDT = 40;
    __shared__ unsigned short As[128 * LDT];
    __shared__ unsigned short Bs[128 * LDT];
    int z = blockIdx.z;
    if (z < 3) {
        if (blockIdx.y != 0) return;
        gemm_core<0>(As, Bs, gatWt + (size_t)z * 512 * 2176 + 128, 2176, 512,
                     W2bf, CTXD, CTXD, Bc + (size_t)z * 512 * KXH + 128, KXH,
                     nullptr, nullptr, blockIdx.x * 128, 0);
    } else {
        if (blockIdx.x != 0) return;
        int zz = z - 3;
        gemm_core<2>(As, Bs, cpre, CTXD, NG, gatWt + (size_t)zz * 512 * 2176 + 128, 2176, CTXD,
                     cW + (size_t)zz * NG * 512, 512, nullptr, nullptr, 0, blockIdx.y * 128);
    }
}

// ---------------- attention logits: a_src/a_dst [N,4] ----------------
__global__ __launch_bounds__(256) void k_att(const unsigned short* __restrict__ xs,
                                             const float* __restrict__ att_s,
                                             const float* __restrict__ att_d,
                                             float* __restrict__ a_src,
                                             float* __restrict__ a_dst, int N) {
    int tid = threadIdx.x, lane = tid & 63, wid = tid >> 6;
    int n = blockIdx.x * 4 + wid;
    if (n >= N) return;
    int h = lane >> 4, c0 = (lane & 15) * 8;
    uint4 raw = *(const uint4*)(xs + (size_t)n * 512 + h * 128 + c0);
    const unsigned short* rs = (const unsigned short*)&raw;
    float ss = 0.f, sd = 0.f;
#pragma unroll
    for (int j = 0; j < 8; j++) {
        float xv = bf2f(rs[j]);
        ss += xv * att_s[h * 128 + c0 + j];
        sd += xv * att_d[h * 128 + c0 + j];
    }
#pragma unroll
    for (int d = 1; d < 16; d <<= 1) {
        ss += __shfl_xor(ss, d);
        sd += __shfl_xor(sd, d);
    }
    if ((lane & 15) == 0) {
        a_src[n * 4 + h] = ss;
        a_dst[n * 4 + h] = sd;
    }
}

// ---------------- CSR build ----------------
__global__ void k_cnt_init(int* cnt, int N) {
    int i = blockIdx.x * 256 + threadIdx.x;
    if (i < N) cnt[i] = 1;  // self-loop
}
__global__ void k_cnt(const int* __restrict__ ei, int E, int* cnt) {
    int i = blockIdx.x * 256 + threadIdx.x;
    if (i < E) atomicAdd(&cnt[ei[E + i]], 1);
}
__global__ __launch_bounds__(1024) void k_scan(const int* __restrict__ cnt, int* __restrict__ rowptr,
                                               int* __restrict__ cursor, int n) {
    __shared__ int wsum[16];
    __shared__ int carry;
    int tid = threadIdx.x, lane = tid & 63, wid = tid >> 6;
    if (tid == 0) carry = 0;
    __syncthreads();
    for (int basei = 0; basei < n; basei += 1024) {
        int i = basei + tid;
        int v = (i < n) ? cnt[i] : 0;
        int s = v;
#pragma unroll
        for (int d = 1; d < 64; d <<= 1) {
            int t = __shfl_up(s, (unsigned)d);
            if (lane >= d) s += t;
        }
        if (lane == 63) wsum[wid] = s;
        __syncthreads();
        if (wid == 0 && lane < 16) {
            int ws = wsum[lane]; int t = ws;
#pragma unroll
            for (int d = 1; d < 16; d <<= 1) {
                int u = __shfl_up(t, (unsigned)d);
                if (lane >= d) t += u;
            }
            wsum[lane] = t - ws;  // exclusive wave offsets
        }
        __syncthreads();
        int excl = carry + wsum[wid] + (s - v);
        if (i < n) { rowptr[i] = excl; cursor[i] = excl; }
        __syncthreads();
        if (tid == 1023) carry += wsum[15] + s;
        __syncthreads();
    }
    if (tid == 0) rowptr[n] = carry;
}
__global__ void k_fill(const int* __restrict__ ei, int E, int N, int* cursor, int* csrc) {
    int i = blockIdx.x * 256 + threadIdx.x;
    if (i >= E + N) return;
    int s, d;
    if (i < E) { s = ei[i]; d = ei[E + i]; }
    else { s = i - E; d = s; }
    int slot = atomicAdd(&cursor[d], 1);
    csrc[slot] = s;
}

// ---------------- GAT aggregation: one-pass softmax + LDS-staged gather ----------------
__global__ __launch_bounds__(256) void k_agg(const int* __restrict__ rowptr,
                                             const int* __restrict__ csrc,
                                             const float* __restrict__ asrc,
                                             const float* __restrict__ adstv,
                                             const unsigned short* __restrict__ xs,
                                             const float* __restrict__ gbias,
                                             const float* __restrict__ bg,
                                             const float* __restrict__ bb,
                                             const float* __restrict__ bm,
                                             const float* __restrict__ bv,
                                             float* __restrict__ x,
                                             unsigned short* __restrict__ xh, int N) {
    __shared__ float wsh[4][64][4];
    __shared__ int ssh[4][64];
    int tid = threadIdx.x, lane = tid & 63, wid = tid >> 6;
    int n = blockIdx.x * 4 + wid;
    if (n >= N) return;
    int beg = rowptr[n], end = rowptr[n + 1];
    float4 ad = *(const float4*)(adstv + (size_t)n * 4);
    int nch = (end - beg + 63) >> 6;
    // phase A: online per-head max & denom (lane i owns edge beg+i of each chunk)
    float m0 = -1e30f, m1 = -1e30f, m2 = -1e30f, m3 = -1e30f;
    float s0 = 0.f, s1 = 0.f, s2 = 0.f, s3 = 0.f;
    float a0 = -1e30f, a1 = -1e30f, a2 = -1e30f, a3 = -1e30f;  // persisted (single-chunk reuse)
    int sv = 0;
    for (int base = beg; base < end; base += 64) {
        int idx = base + lane;
        float b0 = -1e30f, b1 = -1e30f, b2 = -1e30f, b3 = -1e30f;
        int s = 0;
        if (idx < end) {
            s = csrc[idx];
            float4 t = *(const float4*)(asrc + (size_t)s * 4);
            b0 = t.x + ad.x; b0 = b0 > 0.f ? b0 : 0.2f * b0;
            b1 = t.y + ad.y; b1 = b1 > 0.f ? b1 : 0.2f * b1;
            b2 = t.z + ad.z; b2 = b2 > 0.f ? b2 : 0.2f * b2;
            b3 = t.w + ad.w; b3 = b3 > 0.f ? b3 : 0.2f * b3;
        }
        float c0 = b0, c1 = b1, c2 = b2, c3 = b3;
#pragma unroll
        for (int d = 1; d < 64; d <<= 1) {
            c0 = fmaxf(c0, __shfl_xor(c0, d));
            c1 = fmaxf(c1, __shfl_xor(c1, d));
            c2 = fmaxf(c2, __shfl_xor(c2, d));
            c3 = fmaxf(c3, __shfl_xor(c3, d));
        }
        float nm0 = fmaxf(m0, c0), nm1 = fmaxf(m1, c1), nm2 = fmaxf(m2, c2), nm3 = fmaxf(m3, c3);
        float e0 = (idx < end) ? __expf(b0 - nm0) : 0.f;
        float e1 = (idx < end) ? __expf(b1 - nm1) : 0.f;
        float e2 = (idx < end) ? __expf(b2 - nm2) : 0.f;
        float e3 = (idx < end) ? __expf(b3 - nm3) : 0.f;
#pragma unroll
        for (int d = 1; d < 64; d <<= 1) {
            e0 += __shfl_xor(e0, d); e1 += __shfl_xor(e1, d);
            e2 += __shfl_xor(e2, d); e3 += __shfl_xor(e3, d);
        }
        s0 = s0 * __expf(m0 - nm0) + e0; m0 = nm0;
        s1 = s1 * __expf(m1 - nm1) + e1; m1 = nm1;
        s2 = s2 * __expf(m2 - nm2) + e2; m2 = nm2;
        s3 = s3 * __expf(m3 - nm3) + e3; m3 = nm3;
        a0 = b0; a1 = b1; a2 = b2; a3 = b3; sv = s;
    }
    float i0 = 1.f / fmaxf(s0, 1e-16f), i1 = 1.f / fmaxf(s1, 1e-16f);
    float i2 = 1.f / fmaxf(s2, 1e-16f), i3 = 1.f / fmaxf(s3, 1e-16f);
    // phase B: weighted gather, per-edge weights staged in LDS (wave-private)
    const int h = lane >> 4, c0i = (lane & 15) * 8;
    float acc[8];
#pragma unroll
    for (int j = 0; j < 8; j++) acc[j] = 0.f;
    for (int base = beg; base < end; base += 64) {
        int s; float w0, w1, w2, w3;
        if (nch == 1) {
            s = sv;
            w0 = __expf(a0 - m0) * i0; w1 = __expf(a1 - m1) * i1;
            w2 = __expf(a2 - m2) * i2; w3 = __expf(a3 - m3) * i3;
        } else {
            int idx = base + lane;
            float b0 = -1e30f, b1 = -1e30f, b2 = -1e30f, b3 = -1e30f;
            s = 0;
            if (idx < end) {
                s = csrc[idx];
                float4 t = *(const float4*)(asrc + (size_t)s * 4);
                b0 = t.x + ad.x; b0 = b0 > 0.f ? b0 : 0.2f * b0;
                b1 = t.y + ad.y; b1 = b1 > 0.f ? b1 : 0.2f * b1;
                b2 = t.z + ad.z; b2 = b2 > 0.f ? b2 : 0.2f * b2;
                b3 = t.w + ad.w; b3 = b3 > 0.f ? b3 : 0.2f * b3;
            }
            w0 = __expf(b0 - m0) * i0; w1 = __expf(b1 - m1) * i1;
            w2 = __expf(b2 - m2) * i2; w3 = __expf(b3 - m3) * i3;
        }
        ssh[wid][lane] = s;
        wsh[wid][lane][0] = w0; wsh[wid][lane][1] = w1;
        wsh[wid][lane][2] = w2; wsh[wid][lane][3] = w3;
        int cnt = min(64, end - base);
        int i = 0;
        for (; i + 2 <= cnt; i += 2) {
            int sa = ssh[wid][i], sb = ssh[wid][i + 1];
            float wa = wsh[wid][i][h], wb = wsh[wid][i + 1][h];
            uint4 ra = *(const uint4*)(xs + ((size_t)sa << 9) + (h << 7) + c0i);
            uint4 rb = *(const uint4*)(xs + ((size_t)sb << 9) + (h << 7) + c0i);
            const unsigned short* qa = (const unsigned short*)&ra;
            const unsigned short* qb = (const unsigned short*)&rb;
#pragma unroll
            for (int j = 0; j < 8; j++) acc[j] += wa * bf2f(qa[j]);
#pragma unroll
            for (int j = 0; j < 8; j++) acc[j] += wb * bf2f(qb[j]);
        }
        if (i < cnt) {
            int sa = ssh[wid][i];
            float wa = wsh[wid][i][h];
            uint4 ra = *(const uint4*)(xs + ((size_t)sa << 9) + (h << 7) + c0i);
            const unsigned short* qa = (const unsigned short*)&ra;
#pragma unroll
            for (int j = 0; j < 8; j++) acc[j] += wa * bf2f(qa[j]);
        }
    }
    // head mean across lanes (h = lane>>4)
#pragma unroll
    for (int j = 0; j < 8; j++) {
        acc[j] += __shfl_xor(acc[j], 16);
        acc[j] += __shfl_xor(acc[j], 32);
    }
    if (lane < 16) {
#pragma unroll
        for (int j = 0; j < 8; j++) {
            int c = c0i + j;
            float t = acc[j] * 0.25f + gbias[c];
            float sc = bg[c] * rsqrtf(bv[c] + 1e-5f);
            float y = (t - bm[c]) * sc + bb[c];
            float ge = 0.5f * y * (1.f + erff(y * 0.70710678118f));
            float xn = x[(size_t)n * 128 + c] + ge;
            x[(size_t)n * 128 + c] = xn;
            xh[(size_t)n * KXH + c] = f2bf(xn);
        }
    }
}

// ---------------- fused pool + final linear ----------------
__global__ __launch_bounds__(256) void k_pool(const float* __restrict__ x,
                                              const int* __restrict__ batch,
                                              const float* __restrict__ W,
                                              const float* __restrict__ bo,
                                              float* __restrict__ out, int N) {
    __shared__ float xg[128];
    __shared__ float tmp[256];
    __shared__ int bounds[2];
    int g = blockIdx.x, tid = threadIdx.x;
    if (tid < 2) {
        int key = g + tid, lo = 0, hi = N;
        while (lo < hi) { int mid = (lo + hi) >> 1; if (batch[mid] < key) lo = mid + 1; else hi = mid; }
        bounds[tid] = lo;
    }
    __syncthreads();
    int s = bounds[0], e = bounds[1];
    int c = tid & 127, rgp = tid >> 7;
    float a = 0.f;
    for (int n = s + rgp; n < e; n += 2) a += x[(size_t)n * 128 + c];
    tmp[tid] = a;
    __syncthreads();
    if (tid < 128) xg[tid] = tmp[tid] + tmp[tid + 128];
    __syncthreads();
    float cntf = (float)(e - s);
    for (int j = tid; j < 1024; j += 256) {
        float o = cntf * bo[j];
        for (int cc = 0; cc < 128; cc++) o += xg[cc] * W[(size_t)cc * 1024 + j];
        out[(size_t)g * 1024 + j] = o;
    }
}

extern "C" void kernel_launch(void* const* d_in, const int* in_sizes, int n_in,
                              void* d_out, int out_size, void* d_ws, size_t ws_size,
                              hipStream_t stream) {
    const int N = in_sizes[0];
    const int E = in_sizes[2] / 2;
    const int NG = in_sizes[5] / CTXD;
    const int* at = (const int*)d_in[0];
    const float* pos = (const float*)d_in[1];
    const int* ei = (const int*)d_in[2];
    const int* batch = (const int*)d_in[4];
    const float* ctx = (const float*)d_in[5];
    const float* embW = (const float*)d_in[6];
    const float* embB = (const float*)d_in[7];
    const float* W1 = (const float*)d_in[8];
    const float* b1 = (const float*)d_in[9];
    const float* rg = (const float*)d_in[10];
    const float* rb = (const float*)d_in[11];
    const float* rm = (const float*)d_in[12];
    const float* rv = (const float*)d_in[13];
    const float* W2 = (const float*)d_in[14];
    const float* b2 = (const float*)d_in[15];
    const float* gatW = (const float*)d_in[16];
    const float* atts = (const float*)d_in[17];
    const float* attd = (const float*)d_in[18];
    const float* gbias = (const float*)d_in[19];
    const float* bg = (const float*)d_in[20];
    const float* bbb = (const float*)d_in[21];
    const float* bm = (const float*)d_in[22];
    const float* bv = (const float*)d_in[23];
    const float* outW = (const float*)d_in[24];
    const float* outb = (const float*)d_in[25];
    float* out = (float*)d_out;

    char* basep = (char*)d_ws;
    size_t off = 0;
    auto alloc = [&](size_t bytes) -> char* {
        char* p = basep + off;
        off = (off + bytes + 255) & ~(size_t)255;
        return p;
    };
    unsigned short* xh = (unsigned short*)alloc((size_t)N * KXH * 2);
    float* x = (float*)alloc((size_t)N * 128 * 4);
    unsigned short* xs = (unsigned short*)alloc((size_t)N * 512 * 2);
    float* a_src = (float*)alloc((size_t)N * 4 * 4);
    float* a_dst = (float*)alloc((size_t)N * 4 * 4);
    int* cnt = (int*)alloc((size_t)N * 4);
    int* rowptr = (int*)alloc((size_t)(N + 1) * 4);
    int* cursor = (int*)alloc((size_t)N * 4);
    int* csrc = (int*)alloc((size_t)(E + N) * 4);
    unsigned short* gatWt = (unsigned short*)alloc((size_t)NLAYERS * 512 * 2176 * 2);
    unsigned short* W1t = (unsigned short*)alloc((size_t)128 * KPAD * 2);
    unsigned short* W2bf = (unsigned short*)alloc((size_t)128 * CTXD * 2);
    unsigned short* cpre = (unsigned short*)alloc((size_t)NG * CTXD * 2);
    unsigned short* Bc = (unsigned short*)alloc((size_t)NLAYERS * 512 * KXH * 2);
    float* cW = (float*)alloc((size_t)NLAYERS * NG * 512 * 4);
    (void)ws_size; (void)n_in; (void)out_size;

    // ---- weight prep ----
    {
        dim3 b(32, 8);
        dim3 g1((512 + 31) / 32, (2176 + 31) / 32, NLAYERS);
        k_tr<<<g1, b, 0, stream>>>(gatW, gatWt, 2176, 512);
        k_trW1<<<(128 * KPAD + 255) / 256, 256, 0, stream>>>(W1, W1t);
        k_w2bf<<<(128 * CTXD + 255) / 256, 256, 0, stream>>>(W2, W2bf);
        k_cpre<<<(NG * CTXD + 255) / 256, 256, 0, stream>>>(ctx, b2, cpre, NG);
        k_bccopy<<<(NLAYERS * 512 * 128 + 255) / 256, 256, 0, stream>>>(gatWt, Bc);
        dim3 gp(4, 4, 6);
        k_prep<<<gp, 256, 0, stream>>>(gatWt, W2bf, cpre, Bc, cW, NG);
    }
    // ---- node features ----
    k_embed<<<(N * 128 + 255) / 256, 256, 0, stream>>>(at, embW, embB, x, xh, N);
    k_rbf_mfma<<<(N + 127) / 128, 256, 0, stream>>>(pos, W1t, b1, rg, rb, rm, rv, xh, N);
    // ---- CSR (dst-sorted incoming edges incl. self-loops) ----
    k_cnt_init<<<(N + 255) / 256, 256, 0, stream>>>(cnt, N);
    k_cnt<<<(E + 255) / 256, 256, 0, stream>>>(ei, E, cnt);
    k_scan<<<1, 1024, 0, stream>>>(cnt, rowptr, cursor, N);
    k_fill<<<(E + N + 255) / 256, 256, 0, stream>>>(ei, E, N, cursor, csrc);
    // ---- GAT layers ----
    {
        dim3 g((N + 127) / 128, 4, 1);
        for (int l = 0; l < NLAYERS; l++) {
            k_gemm3<<<g, 256, 0, stream>>>(xh, N, Bc + (size_t)l * 512 * KXH,
                                           xs, batch, cW + (size_t)l * NG * 512);
            k_att<<<(N + 3) / 4, 256, 0, stream>>>(xs, atts + l * HEADS * 128, attd + l * HEADS * 128,
                                                   a_src, a_dst, N);
            k_agg<<<(N + 3) / 4, 256, 0, stream>>>(rowptr, csrc, a_src, a_dst, xs,
                                                   gbias + l * 128, bg + l * 128, bbb + l * 128,
                                                   bm + l * 128, bv + l * 128, x, xh, N);
        }
    }
    k_pool<<<NG, 256, 0, stream>>>(x, batch, outW, outb, out, N);
}